// Round 1
// 241.574 us; speedup vs baseline: 1.0994x; 1.0994x over previous
//
#include <hip/hip_runtime.h>
#include <hip/hip_fp16.h>

#define DD 300
#define SS 512
#define VV 50000
#define NF4 75
#define NCH 8

// Workspace layout (float index):
#define CK       0
#define CQ       1
#define CQS      2
#define U_OFF    16       // u  = wk@Wk (300)
#define UQ_OFF   320      // uq = wq@Wq (300)
#define UQWX_OFF 640      // uqWx = Wx^T@uq (300)
#define BC_OFF   960      // bc = Wp@bk+bp (300)
#define WXT_OFF  2048     // WxT[e*300+i] = Wx[i,e] (90000)
#define WCT_OFF  92160    // WcT[e*300+i] = (Wp@Wk)[i,e] (90000)
#define EU_OFF   755200   // eu[v] (50000)
#define E16_OFF  805376   // fp16 emb copy (600 B/row)

#define FMA4(acc, s, v) { acc.x += (s)*(v).x; acc.y += (s)*(v).y; \
                          acc.z += (s)*(v).z; acc.w += (s)*(v).w; }

__device__ __forceinline__ float fast_exp_tanh(float z) {
    const float t = __expf(2.0f * z);
    return __expf(1.0f - 2.0f / (t + 1.0f));
}

// ---------------------------------------------------------------------------
// pre: 203 blocks x 1024.  (unchanged)
// ---------------------------------------------------------------------------
__global__ __launch_bounds__(1024) void pre(
    const float* __restrict__ Wk, const float* __restrict__ bk,
    const float* __restrict__ Wq, const float* __restrict__ bq,
    const float* __restrict__ w_mlp,
    const float* __restrict__ Wp, const float* __restrict__ bp,
    const float* __restrict__ Wx, const float* __restrict__ bx,
    float* __restrict__ ws)
{
    const int blk  = blockIdx.x;
    const int tid  = threadIdx.x;
    const int wv   = tid >> 6;
    const int lane = tid & 63;
    __shared__ __align__(16) float buf[16 * 304 * 3 + 3 * 304];
    __shared__ float red[16];

    if (blk < 100) {
        const int i0 = blk * 3;
        float* sWp = buf + 16 * 304 * 3;
        for (int r = tid; r < 3 * DD; r += 1024)
            sWp[(r / DD) * 304 + (r % DD)] = Wp[i0 * DD + r];
        __syncthreads();

        float4 a00{0,0,0,0}, a01{0,0,0,0}, a10{0,0,0,0},
               a11{0,0,0,0}, a20{0,0,0,0}, a21{0,0,0,0};
        for (int e = wv; e < DD; e += 16) {
            const float4* kr = (const float4*)(Wk + e * DD);
            const float4 k0 = kr[lane];
            const float p0 = sWp[e], p1 = sWp[304 + e], p2 = sWp[608 + e];
            FMA4(a00, p0, k0); FMA4(a10, p1, k0); FMA4(a20, p2, k0);
            if (lane < 11) {
                const float4 k1 = kr[64 + lane];
                FMA4(a01, p0, k1); FMA4(a11, p1, k1); FMA4(a21, p2, k1);
            }
        }
        float4* p0r = (float4*)(buf + (wv * 3 + 0) * 304);
        float4* p1r = (float4*)(buf + (wv * 3 + 1) * 304);
        float4* p2r = (float4*)(buf + (wv * 3 + 2) * 304);
        p0r[lane] = a00; p1r[lane] = a10; p2r[lane] = a20;
        if (lane < 11) { p0r[64+lane] = a01; p1r[64+lane] = a11; p2r[64+lane] = a21; }
        __syncthreads();
        if (tid < DD) {
            #pragma unroll
            for (int r = 0; r < 3; ++r) {
                float s = 0.f;
                for (int w = 0; w < 16; ++w) s += buf[(w * 3 + r) * 304 + tid];
                ws[WCT_OFF + tid * DD + i0 + r] = s;
            }
        }
        return;
    }

    if (blk < 200) {
        const int tb = blk - 100;
        const int bi = tb / 10, bj = tb % 10;
        __shared__ __align__(16) float tile[32][33];
        const int ty = tid >> 5, tx = tid & 31;
        {
            const int r = bi * 32 + ty, c = bj * 32 + tx;
            if (r < DD && c < DD) tile[ty][tx] = Wx[r * DD + c];
        }
        __syncthreads();
        {
            const int ro = bj * 32 + ty, co = bi * 32 + tx;
            if (ro < DD && co < DD) ws[WXT_OFF + ro * DD + co] = tile[tx][ty];
        }
        return;
    }

    if (blk < 202) {
        const float* M  = (blk == 200) ? Wk : Wq;
        const float* vw = (blk == 200) ? w_mlp : (w_mlp + DD);
        float* s_w = buf + 16 * 304;
        float* s_b = buf + 16 * 304 + 304;
        if (tid < DD) {
            s_w[tid] = vw[tid];
            if (blk == 201) s_b[tid] = bk[tid];
        }
        __syncthreads();

        float4 a0{0,0,0,0}, a1{0,0,0,0};
        for (int e = wv; e < DD; e += 16) {
            const float4* kr = (const float4*)(M + e * DD);
            const float s = s_w[e];
            FMA4(a0, s, kr[lane]);
            if (lane < 11) { const float4 k1 = kr[64 + lane]; FMA4(a1, s, k1); }
        }
        float4* pr = (float4*)(buf + wv * 304);
        pr[lane] = a0;
        if (lane < 11) pr[64 + lane] = a1;

        float pk = 0.f;
        if (tid < DD) pk = ((blk == 200) ? bk[tid] : bq[tid]) * s_w[tid];
        #pragma unroll
        for (int off = 32; off; off >>= 1) pk += __shfl_xor(pk, off);
        if (lane == 0) red[wv] = pk;
        __syncthreads();

        const int voff = (blk == 200) ? U_OFF : UQ_OFF;
        if (tid < DD) {
            float s = 0.f;
            #pragma unroll
            for (int w = 0; w < 16; ++w) s += buf[w * 304 + tid];
            ws[voff + tid] = s;
        }
        if (tid == 0) {
            float s = 0.f;
            for (int w = 0; w < 16; ++w) s += red[w];
            ws[(blk == 200) ? CK : CQ] = s;
        }
        if (blk == 201) {
            const float4* b4 = (const float4*)s_b;
            const float4 k0 = b4[lane];
            const float4 k1 = (lane < 11) ? b4[64 + lane] : float4{0, 0, 0, 0};
            for (int i2 = wv; i2 < DD; i2 += 16) {
                const float4* wr = (const float4*)(Wp + i2 * DD);
                const float4 w0 = wr[lane];
                float a = w0.x * k0.x + w0.y * k0.y + w0.z * k0.z + w0.w * k0.w;
                if (lane < 11) {
                    const float4 w1 = wr[64 + lane];
                    a += w1.x * k1.x + w1.y * k1.y + w1.z * k1.z + w1.w * k1.w;
                }
                #pragma unroll
                for (int off = 32; off; off >>= 1) a += __shfl_xor(a, off);
                if (lane == 0) ws[BC_OFF + i2] = a + bp[i2];
            }
        }
        return;
    }

    // blk 202: recompute uq locally, then uqWx = uq@Wx, c_qs.
    {
        float* s_w = buf + 16 * 304;        // wq
        float* s_u = buf + 16 * 304 + 304;  // uq (full)
        if (tid < DD) s_w[tid] = w_mlp[DD + tid];
        __syncthreads();

        float4 a0{0,0,0,0}, a1{0,0,0,0};
        for (int e = wv; e < DD; e += 16) {
            const float4* kr = (const float4*)(Wq + e * DD);
            const float s = s_w[e];
            FMA4(a0, s, kr[lane]);
            if (lane < 11) { const float4 k1 = kr[64 + lane]; FMA4(a1, s, k1); }
        }
        float4* pr = (float4*)(buf + wv * 304);
        pr[lane] = a0;
        if (lane < 11) pr[64 + lane] = a1;
        __syncthreads();
        if (tid < DD) {
            float s = 0.f;
            #pragma unroll
            for (int w = 0; w < 16; ++w) s += buf[w * 304 + tid];
            s_u[tid] = s;
        }
        __syncthreads();

        float4 b0{0,0,0,0}, b1{0,0,0,0};
        for (int i2 = wv; i2 < DD; i2 += 16) {
            const float4* xr = (const float4*)(Wx + i2 * DD);
            const float s = s_u[i2];
            FMA4(b0, s, xr[lane]);
            if (lane < 11) { const float4 x1 = xr[64 + lane]; FMA4(b1, s, x1); }
        }
        float pk = 0.f;
        if (tid < DD) pk = bq[tid] * s_w[tid] + s_u[tid] * bx[tid];
        #pragma unroll
        for (int off = 32; off; off >>= 1) pk += __shfl_xor(pk, off);
        if (lane == 0) red[wv] = pk;
        __syncthreads();
        float4* qr = (float4*)(buf + wv * 304);
        qr[lane] = b0;
        if (lane < 11) qr[64 + lane] = b1;
        __syncthreads();
        if (tid < DD) {
            float s = 0.f;
            #pragma unroll
            for (int w = 0; w < 16; ++w) s += buf[w * 304 + tid];
            ws[UQWX_OFF + tid] = s;
        }
        if (tid == 0) {
            float s = 0.f;
            for (int w = 0; w < 16; ++w) s += red[w];
            ws[CQS] = s;
        }
    }
}

// ---------------------------------------------------------------------------
// tables: eu[v] = dot(emb[v], u) + fp16 emb copy. 512 x 1024. (unchanged)
// ---------------------------------------------------------------------------
__global__ __launch_bounds__(1024) void build_tables(
    const float* __restrict__ emb, float* __restrict__ ws, const int do16)
{
    const int tid  = threadIdx.x;
    const int wv   = tid >> 6;
    const int lane = tid & 63;
    __shared__ __align__(16) float u_s[DD];
    if (tid < DD) u_s[tid] = ws[U_OFF + tid];
    __syncthreads();

    const float4* u4 = (const float4*)u_s;
    const float4  q0 = u4[lane];
    const float4  q1 = (lane < 11) ? u4[64 + lane] : float4{0, 0, 0, 0};
    ushort4* e16 = (ushort4*)(ws + E16_OFF);

    const int gw     = blockIdx.x * 16 + wv;
    const int stride = gridDim.x * 16;
    for (int v = gw; v < VV; v += stride) {
        const float4* er = (const float4*)(emb + (size_t)v * DD);
        const float4 e0 = er[lane];
        float4 e1{0, 0, 0, 0};
        float a = e0.x * q0.x + e0.y * q0.y + e0.z * q0.z + e0.w * q0.w;
        if (lane < 11) {
            e1 = er[64 + lane];
            a += e1.x * q1.x + e1.y * q1.y + e1.z * q1.z + e1.w * q1.w;
        }
        #pragma unroll
        for (int off = 32; off; off >>= 1) a += __shfl_xor(a, off);
        if (lane == 0) ws[EU_OFF + v] = a;
        if (do16) {
            ushort4 h0;
            h0.x = __half_as_ushort(__float2half(e0.x));
            h0.y = __half_as_ushort(__float2half(e0.y));
            h0.z = __half_as_ushort(__float2half(e0.z));
            h0.w = __half_as_ushort(__float2half(e0.w));
            e16[(size_t)v * NF4 + lane] = h0;
            if (lane < 11) {
                ushort4 h1;
                h1.x = __half_as_ushort(__float2half(e1.x));
                h1.y = __half_as_ushort(__float2half(e1.y));
                h1.z = __half_as_ushort(__float2half(e1.z));
                h1.w = __half_as_ushort(__float2half(e1.w));
                e16[(size_t)v * NF4 + 64 + lane] = h1;
            }
        }
    }
}

// ---------------------------------------------------------------------------
// k_hops: 256 blocks x 1024 threads, 2 batch rows per block. Does the
// ENTIRE per-row pipeline (init + 3 hops) in LDS — no atomics, no global
// intermediates, 1 launch instead of 7.
//   init : tokens/len/ks, aspect-mean X0, XN = X0@WxT+bx, qs0
//   hop  : p = exp(tanh(ks+qs)); m = sum p*w*e16[t] (16 waves, 8 chunks/row);
//          X = (m/sp)@WcT+bc+XN; [last: out = X@Wd^T+bd]
//          [else: XN = X@WxT+bx; qs = X·uqWx+cqs]
// ---------------------------------------------------------------------------
__global__ __launch_bounds__(1024) void k_hops(
    const int* __restrict__ text, const int* __restrict__ asp,
    const float* __restrict__ emb, const float* __restrict__ bx,
    const float* __restrict__ Wd, const float* __restrict__ bd,
    float* __restrict__ out, float* __restrict__ ws, const int use16)
{
    const int b0   = blockIdx.x * 2;
    const int tid  = threadIdx.x;
    const int wv   = tid >> 6;     // 0..15
    const int lane = tid & 63;
    const int bb   = tid >> 9;     // row within pair (0/1)
    const int s    = tid & 511;    // sequence position

    __shared__ int   stok[2][512];
    __shared__ float ks  [2][512];
    __shared__ float cw  [2][512];
    __shared__ __align__(16) float As[2][304];
    __shared__ __align__(16) float XN[2][304];
    __shared__ __align__(16) float mpart[16][304];   // also GEMM partials
    __shared__ float red[16];
    __shared__ float isp[2], qsv[2];
    __shared__ int   s0v[2], lenv[2];

    float* part = &mpart[0][0];
#define PART(g, r, i) part[(((g) * 2 + (r)) * 304) + (i)]

    const float ck  = ws[CK];
    const float cqs = ws[CQS];

    // ---- init: tokens + len ----
    const int t = text[(b0 + bb) * SS + s];
    stok[bb][s] = t;
    {
        const unsigned long long bal = __ballot(t != 0);
        if (lane == 0) red[wv] = (float)__popcll(bal);
    }
    __syncthreads();
    if (tid < 2) {
        int len = 0;
        #pragma unroll
        for (int w = 0; w < 8; ++w) len += (int)red[tid * 8 + w];
        lenv[tid] = len;
        s0v[tid]  = SS - len;
    }
    // aspect mean -> As (X0); coalesced across i
    if (tid < 608) {
        const int ab = tid / 304, i2 = tid - ab * 304;
        if (i2 < DD) {
            float na = 0.f, a = 0.f;
            #pragma unroll
            for (int k = 0; k < 8; ++k) {
                const int idx = asp[(b0 + ab) * 8 + k];
                na += (idx != 0) ? 1.0f : 0.0f;
                a  += emb[(size_t)idx * DD + i2];
            }
            As[ab][i2] = a / na;
        }
    }
    __syncthreads();
    // ks row (hop-invariant)
    {
        const int j = s - s0v[bb];
        const float wg = (j >= 0) ? (1.0f - (float)j / (float)lenv[bb]) : 1.0f;
        ks[bb][s] = wg * ws[EU_OFF + t] + ck;
    }

    const int g = tid / 304;
    const int i = tid - g * 304;
    const bool act = (g < 3) && (i < DD);

    // XN = X0 @ WxT + bx
    if (act) {
        const float* W = ws + WXT_OFF;
        const int e0 = g * 100;
        float a0 = 0.f, a1 = 0.f;
        for (int e = e0; e < e0 + 100; e += 2) {
            const float w0 = W[e * DD + i];
            const float w1 = W[(e + 1) * DD + i];
            a0 += As[0][e] * w0 + As[0][e + 1] * w1;
            a1 += As[1][e] * w0 + As[1][e + 1] * w1;
        }
        PART(g, 0, i) = a0; PART(g, 1, i) = a1;
    }
    __syncthreads();
    for (int idx = tid; idx < 2 * DD; idx += 1024) {
        const int r = idx / DD, e = idx - r * DD;
        XN[r][e] = PART(0, r, e) + PART(1, r, e) + PART(2, r, e) + bx[e];
    }
    // qs0 = dot(X0, uqWx) + cqs
    if (wv < 2) {
        const float4* x4 = (const float4*)As[wv];
        const float4* q4 = (const float4*)(ws + UQWX_OFF);
        const float4 xa = x4[lane], ua = q4[lane];
        float a = xa.x * ua.x + xa.y * ua.y + xa.z * ua.z + xa.w * ua.w;
        if (lane < 11) {
            const float4 xb = x4[64 + lane], ub = q4[64 + lane];
            a += xb.x * ub.x + xb.y * ub.y + xb.z * ub.z + xb.w * ub.w;
        }
        #pragma unroll
        for (int off = 32; off; off >>= 1) a += __shfl_xor(a, off);
        if (lane == 0) qsv[wv] = a + cqs;
    }

    // ---- 3 hops ----
    for (int h = 0; h < 3; ++h) {
        __syncthreads();   // qsv ready; As safe to reuse
        // scores: p = exp(tanh(ks+qs)); cw = p*w; row-reduce p
        {
            const float qs = qsv[bb];
            const int s0 = s0v[bb];
            float p = 0.f;
            if (s >= s0) {
                p = fast_exp_tanh(ks[bb][s] + qs);
                cw[bb][s] = p * (1.0f - (float)(s - s0) / (float)lenv[bb]);
            }
            #pragma unroll
            for (int off = 32; off; off >>= 1) p += __shfl_xor(p, off);
            if (lane == 0) red[wv] = p;
        }
        __syncthreads();
        if (tid < 2) {
            float sp = 0.f;
            #pragma unroll
            for (int w = 0; w < 8; ++w) sp += red[tid * 8 + w];
            const int s0 = s0v[tid];
            if (s0 > 0) sp += (float)s0 * fast_exp_tanh(ck + qsv[tid]);
            isp[tid] = 1.0f / sp;
        }
        // gather: wave wv = (row wv>>3, chunk wv&7)
        {
            const int rb = wv >> 3, ch = wv & 7;
            const int s0 = s0v[rb];
            const int q  = (lenv[rb] + NCH - 1) >> 3;
            const int sb = s0 + ch * q;
            const int se = min(sb + q, SS);
            float4 acc{0, 0, 0, 0}, accb{0, 0, 0, 0};
            if (sb < se) {
                if (use16) {
                    const ushort4* e16 = (const ushort4*)(ws + E16_OFF);
                    ushort4 ca[4] = {}, cb[4] = {};
                    #pragma unroll
                    for (int k = 0; k < 4; ++k) {
                        const int r = sb + k;
                        if (r < se) {
                            const ushort4* rp = e16 + (size_t)stok[rb][r] * NF4;
                            ca[k] = rp[lane];
                            if (lane < 11) cb[k] = rp[64 + lane];
                        }
                    }
                    for (int base = sb; base < se; base += 4) {
                        ushort4 na[4] = {}, nb[4] = {};
                        #pragma unroll
                        for (int k = 0; k < 4; ++k) {
                            const int rn = base + 4 + k;
                            if (rn < se) {
                                const ushort4* rp = e16 + (size_t)stok[rb][rn] * NF4;
                                na[k] = rp[lane];
                                if (lane < 11) nb[k] = rp[64 + lane];
                            }
                        }
                        #pragma unroll
                        for (int k = 0; k < 4; ++k) {
                            const int r = base + k;
                            if (r < se) {
                                const float cc = cw[rb][r];
                                const float2 f0 = __half22float2(*(const __half2*)&ca[k].x);
                                const float2 f1 = __half22float2(*(const __half2*)&ca[k].z);
                                acc.x += cc * f0.x; acc.y += cc * f0.y;
                                acc.z += cc * f1.x; acc.w += cc * f1.y;
                                if (lane < 11) {
                                    const float2 g0 = __half22float2(*(const __half2*)&cb[k].x);
                                    const float2 g1 = __half22float2(*(const __half2*)&cb[k].z);
                                    accb.x += cc * g0.x; accb.y += cc * g0.y;
                                    accb.z += cc * g1.x; accb.w += cc * g1.y;
                                }
                            }
                        }
                        #pragma unroll
                        for (int k = 0; k < 4; ++k) { ca[k] = na[k]; cb[k] = nb[k]; }
                    }
                } else {
                    for (int r = sb; r < se; ++r) {
                        const float cc = cw[rb][r];
                        const float4* er = (const float4*)(emb + (size_t)stok[rb][r] * DD);
                        const float4 f = er[lane];
                        acc.x += cc * f.x; acc.y += cc * f.y;
                        acc.z += cc * f.z; acc.w += cc * f.w;
                        if (lane < 11) {
                            const float4 f1 = er[64 + lane];
                            accb.x += cc * f1.x; accb.y += cc * f1.y;
                            accb.z += cc * f1.z; accb.w += cc * f1.w;
                        }
                    }
                }
            }
            ((float4*)&mpart[wv][0])[lane] = acc;
            if (lane < 11) ((float4*)&mpart[wv][0])[64 + lane] = accb;
        }
        __syncthreads();
        // reduce 8 chunk-partials per row, normalize -> As = m/sp
        for (int idx = tid; idx < 2 * DD; idx += 1024) {
            const int r = idx / DD, j = idx - r * DD;
            float m = 0.f;
            #pragma unroll
            for (int w = 0; w < 8; ++w) m += mpart[r * 8 + w][j];
            As[r][j] = m * isp[r];
        }
        __syncthreads();
        // GEMM1: X = As@WcT + bc + XN
        if (act) {
            const float* W = ws + WCT_OFF;
            const int e0 = g * 100;
            float a0 = 0.f, a1 = 0.f;
            for (int e = e0; e < e0 + 100; e += 2) {
                const float w0 = W[e * DD + i];
                const float w1 = W[(e + 1) * DD + i];
                a0 += As[0][e] * w0 + As[0][e + 1] * w1;
                a1 += As[1][e] * w0 + As[1][e + 1] * w1;
            }
            PART(g, 0, i) = a0; PART(g, 1, i) = a1;
        }
        __syncthreads();
        for (int idx = tid; idx < 2 * DD; idx += 1024) {
            const int r = idx / DD, e = idx - r * DD;
            As[r][e] = PART(0, r, e) + PART(1, r, e) + PART(2, r, e)
                     + ws[BC_OFF + e] + XN[r][e];
        }
        __syncthreads();
        if (h == 2) {
            if (wv < 6) {
                const int r = wv / 3, p = wv - r * 3;
                const float4* wr = (const float4*)(Wd + p * DD);
                const float4* x4 = (const float4*)As[r];
                const float4 w0 = wr[lane], v0 = x4[lane];
                float a = w0.x * v0.x + w0.y * v0.y + w0.z * v0.z + w0.w * v0.w;
                if (lane < 11) {
                    const float4 w1 = wr[64 + lane], v1 = x4[64 + lane];
                    a += w1.x * v1.x + w1.y * v1.y + w1.z * v1.z + w1.w * v1.w;
                }
                #pragma unroll
                for (int off = 32; off; off >>= 1) a += __shfl_xor(a, off);
                if (lane == 0) out[(b0 + r) * 3 + p] = a + bd[p];
            }
        } else {
            // GEMM2: XN = As@WxT + bx
            if (act) {
                const float* W = ws + WXT_OFF;
                const int e0 = g * 100;
                float a0 = 0.f, a1 = 0.f;
                for (int e = e0; e < e0 + 100; e += 2) {
                    const float w0 = W[e * DD + i];
                    const float w1 = W[(e + 1) * DD + i];
                    a0 += As[0][e] * w0 + As[0][e + 1] * w1;
                    a1 += As[1][e] * w0 + As[1][e + 1] * w1;
                }
                PART(g, 0, i) = a0; PART(g, 1, i) = a1;
            }
            __syncthreads();
            for (int idx = tid; idx < 2 * DD; idx += 1024) {
                const int r = idx / DD, e = idx - r * DD;
                XN[r][e] = PART(0, r, e) + PART(1, r, e) + PART(2, r, e) + bx[e];
            }
            // qs update = dot(X, uqWx) + cqs
            if (wv < 2) {
                const float4* x4 = (const float4*)As[wv];
                const float4* q4 = (const float4*)(ws + UQWX_OFF);
                const float4 xa = x4[lane], ua = q4[lane];
                float a = xa.x * ua.x + xa.y * ua.y + xa.z * ua.z + xa.w * ua.w;
                if (lane < 11) {
                    const float4 xb = x4[64 + lane], ub = q4[64 + lane];
                    a += xb.x * ub.x + xb.y * ub.y + xb.z * ub.z + xb.w * ub.w;
                }
                #pragma unroll
                for (int off = 32; off; off >>= 1) a += __shfl_xor(a, off);
                if (lane == 0) qsv[wv] = a + cqs;
            }
        }
    }
#undef PART
}

extern "C" void kernel_launch(void* const* d_in, const int* in_sizes, int n_in,
                              void* d_out, int out_size, void* d_ws, size_t ws_size,
                              hipStream_t stream)
{
    const int*   text = (const int*)d_in[0];
    const int*   asp  = (const int*)d_in[1];
    const float* emb  = (const float*)d_in[2];
    const float* Wx   = (const float*)d_in[3];
    const float* bx   = (const float*)d_in[4];
    const float* Wk   = (const float*)d_in[5];
    const float* bk   = (const float*)d_in[6];
    const float* Wq   = (const float*)d_in[7];
    const float* bq   = (const float*)d_in[8];
    const float* wm   = (const float*)d_in[9];
    const float* Wp   = (const float*)d_in[10];
    const float* bp   = (const float*)d_in[11];
    const float* Wd   = (const float*)d_in[12];
    const float* bd   = (const float*)d_in[13];
    float* out = (float*)d_out;
    float* ws  = (float*)d_ws;

    const size_t need = (size_t)E16_OFF * 4 + (size_t)VV * DD * 2;
    const int use16 = (ws_size >= need) ? 1 : 0;

    pre<<<203, 1024, 0, stream>>>(Wk, bk, Wq, bq, wm, Wp, bp, Wx, bx, ws);
    build_tables<<<512, 1024, 0, stream>>>(emb, ws, use16);
    k_hops<<<256, 1024, 0, stream>>>(text, asp, emb, bx, Wd, bd, out, ws, use16);
}

// Round 2
// 229.443 us; speedup vs baseline: 1.1575x; 1.0529x over previous
//
#include <hip/hip_runtime.h>
#include <hip/hip_fp16.h>

#define DD 300
#define SS 512
#define VV 50000
#define NF4 75

// Workspace layout (float index):
#define CK       0
#define CQ       1
#define CQS      2
#define BU_OFF   3        // B·u
#define BW1_OFF  4        // B·w1
#define U_OFF    16       // u_emb = wk@Wk (300)  [for EU table]
#define UQ_OFF   320      // uq = wq@Wq (300)
#define UQWX_OFF 640      // u = Wx^T@uq (300)
#define BCB_OFF  960      // B = Wp@bk+bp+bx (300)
#define W1_OFF   1280     // w1 = Wx^T@u
#define W2_OFF   1600     // w2 = (Wx^2)^T@u
#define X2_OFF   2048     // Wx^2 row-major (90000)
#define C_OFF    92160    // C = Wp@Wk row-major (90000)
#define P1_OFF   182272   // C^T@u
#define P2_OFF   182592   // C^T@w1
#define D0_OFF   182912   // F3 = Wd@Wx^3 (3x300)
#define D1_OFF   183872   // F2@C
#define D2_OFF   184832   // F1@C
#define D3_OFF   185792   // Wd@C
#define C3A_OFF  186752   // F1@B (3)
#define C3B_OFF  186768   // F2@B (3)
#define C3C_OFF  186784   // Wd@B + bd (3)
#define EU_OFF   755200   // eu[v] (50000)
#define E16_OFF  805376   // fp16 emb copy (600 B/row)

#define FMA4(acc, s, v) { acc.x += (s)*(v).x; acc.y += (s)*(v).y; \
                          acc.z += (s)*(v).z; acc.w += (s)*(v).w; }

__device__ __forceinline__ float fast_exp_tanh(float z) {
    const float t = __expf(2.0f * z);
    return __expf(1.0f - 2.0f / (t + 1.0f));
}

__device__ __forceinline__ float wred(float v) {
    #pragma unroll
    for (int off = 32; off; off >>= 1) v += __shfl_xor(v, off);
    return v;
}

// ---------------------------------------------------------------------------
// pre: 203 blocks x 1024.
//   0..99  : C = Wp@Wk rows (row-major store)
//   100..199: X2 = Wx@Wx rows (row-major store)
//   200    : u_emb = wk@Wk, c_k
//   201    : uq = wq@Wq, c_q, B = Wp@bk+bp+bx
//   202    : u = uq@Wx, c_qs
// ---------------------------------------------------------------------------
__global__ __launch_bounds__(1024) void pre(
    const float* __restrict__ Wk, const float* __restrict__ bk,
    const float* __restrict__ Wq, const float* __restrict__ bq,
    const float* __restrict__ w_mlp,
    const float* __restrict__ Wp, const float* __restrict__ bp,
    const float* __restrict__ Wx, const float* __restrict__ bx,
    float* __restrict__ ws)
{
    const int blk  = blockIdx.x;
    const int tid  = threadIdx.x;
    const int wv   = tid >> 6;
    const int lane = tid & 63;
    __shared__ __align__(16) float buf[16 * 304 * 3 + 3 * 304];
    __shared__ float red[16];

    if (blk < 200) {
        const bool isC = (blk < 100);
        const int i0 = (isC ? blk : blk - 100) * 3;
        const float* Arows = isC ? Wp : Wx;   // rows i0..i0+2 of this
        const float* Mrows = isC ? Wk : Wx;   // combined rows
        const int outoff = isC ? C_OFF : X2_OFF;

        float* sWp = buf + 16 * 304 * 3;
        for (int r = tid; r < 3 * DD; r += 1024)
            sWp[(r / DD) * 304 + (r % DD)] = Arows[i0 * DD + r];
        __syncthreads();

        float4 a00{0,0,0,0}, a01{0,0,0,0}, a10{0,0,0,0},
               a11{0,0,0,0}, a20{0,0,0,0}, a21{0,0,0,0};
        for (int e = wv; e < DD; e += 16) {
            const float4* kr = (const float4*)(Mrows + e * DD);
            const float4 k0 = kr[lane];
            const float p0 = sWp[e], p1 = sWp[304 + e], p2 = sWp[608 + e];
            FMA4(a00, p0, k0); FMA4(a10, p1, k0); FMA4(a20, p2, k0);
            if (lane < 11) {
                const float4 k1 = kr[64 + lane];
                FMA4(a01, p0, k1); FMA4(a11, p1, k1); FMA4(a21, p2, k1);
            }
        }
        float4* p0r = (float4*)(buf + (wv * 3 + 0) * 304);
        float4* p1r = (float4*)(buf + (wv * 3 + 1) * 304);
        float4* p2r = (float4*)(buf + (wv * 3 + 2) * 304);
        p0r[lane] = a00; p1r[lane] = a10; p2r[lane] = a20;
        if (lane < 11) { p0r[64+lane] = a01; p1r[64+lane] = a11; p2r[64+lane] = a21; }
        __syncthreads();
        if (tid < DD) {
            #pragma unroll
            for (int r = 0; r < 3; ++r) {
                float s = 0.f;
                for (int w = 0; w < 16; ++w) s += buf[(w * 3 + r) * 304 + tid];
                ws[outoff + (i0 + r) * DD + tid] = s;
            }
        }
        return;
    }

    if (blk < 202) {
        const float* M  = (blk == 200) ? Wk : Wq;
        const float* vw = (blk == 200) ? w_mlp : (w_mlp + DD);
        float* s_w = buf + 16 * 304;
        float* s_b = buf + 16 * 304 + 304;
        if (tid < DD) {
            s_w[tid] = vw[tid];
            if (blk == 201) s_b[tid] = bk[tid];
        }
        __syncthreads();

        float4 a0{0,0,0,0}, a1{0,0,0,0};
        for (int e = wv; e < DD; e += 16) {
            const float4* kr = (const float4*)(M + e * DD);
            const float s = s_w[e];
            FMA4(a0, s, kr[lane]);
            if (lane < 11) { const float4 k1 = kr[64 + lane]; FMA4(a1, s, k1); }
        }
        float4* pr = (float4*)(buf + wv * 304);
        pr[lane] = a0;
        if (lane < 11) pr[64 + lane] = a1;

        float pk = 0.f;
        if (tid < DD) pk = ((blk == 200) ? bk[tid] : bq[tid]) * s_w[tid];
        pk = wred(pk);
        if (lane == 0) red[wv] = pk;
        __syncthreads();

        const int voff = (blk == 200) ? U_OFF : UQ_OFF;
        if (tid < DD) {
            float s = 0.f;
            #pragma unroll
            for (int w = 0; w < 16; ++w) s += buf[w * 304 + tid];
            ws[voff + tid] = s;
        }
        if (tid == 0) {
            float s = 0.f;
            for (int w = 0; w < 16; ++w) s += red[w];
            ws[(blk == 200) ? CK : CQ] = s;
        }
        if (blk == 201) {
            const float4* b4 = (const float4*)s_b;
            const float4 k0 = b4[lane];
            const float4 k1 = (lane < 11) ? b4[64 + lane] : float4{0, 0, 0, 0};
            for (int i2 = wv; i2 < DD; i2 += 16) {
                const float4* wr = (const float4*)(Wp + i2 * DD);
                const float4 w0 = wr[lane];
                float a = w0.x * k0.x + w0.y * k0.y + w0.z * k0.z + w0.w * k0.w;
                if (lane < 11) {
                    const float4 w1 = wr[64 + lane];
                    a += w1.x * k1.x + w1.y * k1.y + w1.z * k1.z + w1.w * k1.w;
                }
                a = wred(a);
                if (lane == 0) ws[BCB_OFF + i2] = a + bp[i2] + bx[i2];
            }
        }
        return;
    }

    // blk 202: uq recomputed locally -> u = uq@Wx, c_qs.
    {
        float* s_w = buf + 16 * 304;        // wq
        float* s_u = buf + 16 * 304 + 304;  // uq (full)
        if (tid < DD) s_w[tid] = w_mlp[DD + tid];
        __syncthreads();

        float4 a0{0,0,0,0}, a1{0,0,0,0};
        for (int e = wv; e < DD; e += 16) {
            const float4* kr = (const float4*)(Wq + e * DD);
            const float s = s_w[e];
            FMA4(a0, s, kr[lane]);
            if (lane < 11) { const float4 k1 = kr[64 + lane]; FMA4(a1, s, k1); }
        }
        float4* pr = (float4*)(buf + wv * 304);
        pr[lane] = a0;
        if (lane < 11) pr[64 + lane] = a1;
        __syncthreads();
        if (tid < DD) {
            float s = 0.f;
            #pragma unroll
            for (int w = 0; w < 16; ++w) s += buf[w * 304 + tid];
            s_u[tid] = s;
        }
        __syncthreads();

        float4 b0{0,0,0,0}, b1{0,0,0,0};
        for (int i2 = wv; i2 < DD; i2 += 16) {
            const float4* xr = (const float4*)(Wx + i2 * DD);
            const float s = s_u[i2];
            FMA4(b0, s, xr[lane]);
            if (lane < 11) { const float4 x1 = xr[64 + lane]; FMA4(b1, s, x1); }
        }
        float pk = 0.f;
        if (tid < DD) pk = bq[tid] * s_w[tid] + s_u[tid] * bx[tid];
        pk = wred(pk);
        if (lane == 0) red[wv] = pk;
        __syncthreads();
        float4* qr = (float4*)(buf + wv * 304);
        qr[lane] = b0;
        if (lane < 11) qr[64 + lane] = b1;
        __syncthreads();
        if (tid < DD) {
            float s = 0.f;
            #pragma unroll
            for (int w = 0; w < 16; ++w) s += buf[w * 304 + tid];
            ws[UQWX_OFF + tid] = s;
        }
        if (tid == 0) {
            float s = 0.f;
            for (int w = 0; w < 16; ++w) s += red[w];
            ws[CQS] = s;
        }
    }
}

// ---------------------------------------------------------------------------
// rowcomb3: sOut[r][:] = sum_i sIn[r][i] * M[i][:]  (M 300x300 row-major).
// All 1024 threads participate; internal barriers.
// ---------------------------------------------------------------------------
__device__ __forceinline__ void rowcomb3(
    const float* __restrict__ M, const float (*sIn)[304], float (*sOut)[304],
    float* __restrict__ buf, const int tid, const int wv, const int lane)
{
    float4 a00{0,0,0,0}, a01{0,0,0,0}, a10{0,0,0,0},
           a11{0,0,0,0}, a20{0,0,0,0}, a21{0,0,0,0};
    for (int e = wv; e < DD; e += 16) {
        const float4* kr = (const float4*)(M + e * DD);
        const float4 k0 = kr[lane];
        const float p0 = sIn[0][e], p1 = sIn[1][e], p2 = sIn[2][e];
        FMA4(a00, p0, k0); FMA4(a10, p1, k0); FMA4(a20, p2, k0);
        if (lane < 11) {
            const float4 k1 = kr[64 + lane];
            FMA4(a01, p0, k1); FMA4(a11, p1, k1); FMA4(a21, p2, k1);
        }
    }
    float4* p0r = (float4*)(buf + (wv * 3 + 0) * 304);
    float4* p1r = (float4*)(buf + (wv * 3 + 1) * 304);
    float4* p2r = (float4*)(buf + (wv * 3 + 2) * 304);
    p0r[lane] = a00; p1r[lane] = a10; p2r[lane] = a20;
    if (lane < 11) { p0r[64+lane] = a01; p1r[64+lane] = a11; p2r[64+lane] = a21; }
    __syncthreads();
    if (tid < DD) {
        #pragma unroll
        for (int r = 0; r < 3; ++r) {
            float s = 0.f;
            for (int w = 0; w < 16; ++w) s += buf[(w * 3 + r) * 304 + tid];
            sOut[r][tid] = s;
        }
    }
    __syncthreads();
}

// ---------------------------------------------------------------------------
// tables: blocks 0..5 = preB (composed matrices/vectors); blocks 6..517 =
// eu[v] = dot(emb[v], u_emb) + fp16 emb copy.
// ---------------------------------------------------------------------------
__global__ __launch_bounds__(1024) void build_tables(
    const float* __restrict__ emb,
    const float* __restrict__ Wx, const float* __restrict__ Wp,
    const float* __restrict__ Wk, const float* __restrict__ Wd,
    const float* __restrict__ bd,
    float* __restrict__ ws, const int do16)
{
    const int blk  = blockIdx.x;
    const int tid  = threadIdx.x;
    const int wv   = tid >> 6;
    const int lane = tid & 63;
    __shared__ __align__(16) float buf[16 * 304 * 3];
    __shared__ __align__(16) float sA[3][304];
    __shared__ __align__(16) float sB[3][304];
    __shared__ __align__(16) float u_s[DD];

    if (blk < 6) {
        const float* C  = ws + C_OFF;
        const float* X2 = ws + X2_OFF;

#define LOADWD()  { for (int r = tid; r < 3 * DD; r += 1024) \
                        sA[r / DD][r % DD] = Wd[r]; __syncthreads(); }
#define ZERO_A()  { for (int r = tid; r < 3 * 304; r += 1024) \
                        ((float*)sA)[r] = 0.f; __syncthreads(); }
#define STORE3(S, off) { for (int r = tid; r < 3 * DD; r += 1024) \
                             ws[(off) + r] = S[r / DD][r % DD]; }
#define DOTB3(S, off, addbd) if (wv < 3) { \
        float a = 0.f; \
        for (int i = lane; i < DD; i += 64) a += S[wv][i] * ws[BCB_OFF + i]; \
        a = wred(a); \
        if (lane == 0) ws[(off) + wv] = a + ((addbd) ? bd[wv] : 0.f); }
#define DOTB1(S, off) if (wv == 0) { \
        float a = 0.f; \
        for (int i = lane; i < DD; i += 64) a += S[i] * ws[BCB_OFF + i]; \
        a = wred(a); \
        if (lane == 0) ws[off] = a; }

        if (blk == 0) {          // F1 = Wd@Wx ; c3a = F1@B ; D2 = F1@C
            LOADWD();
            rowcomb3(Wx, sA, sB, buf, tid, wv, lane);
            DOTB3(sB, C3A_OFF, false);
            rowcomb3(C, sB, sA, buf, tid, wv, lane);
            STORE3(sA, D2_OFF);
        } else if (blk == 1) {   // F2 = Wd@X2 ; c3b ; D1 = F2@C ; D0 = F2@Wx
            LOADWD();
            rowcomb3(X2, sA, sB, buf, tid, wv, lane);
            DOTB3(sB, C3B_OFF, false);
            rowcomb3(C, sB, sA, buf, tid, wv, lane);
            STORE3(sA, D1_OFF);
            rowcomb3(Wx, sB, sA, buf, tid, wv, lane);
            STORE3(sA, D0_OFF);
        } else if (blk == 2) {   // c3c = Wd@B+bd ; D3 = (Wd@Wp)@Wk
            LOADWD();
            DOTB3(sA, C3C_OFF, true);
            rowcomb3(Wp, sA, sB, buf, tid, wv, lane);
            rowcomb3(Wk, sB, sA, buf, tid, wv, lane);
            STORE3(sA, D3_OFF);
        } else if (blk == 3) {   // w1 = uq-comb X2 ; bw1 ; p2 = w1-comb C
            ZERO_A();
            if (tid < DD) sA[0][tid] = ws[UQ_OFF + tid];
            __syncthreads();
            rowcomb3(X2, sA, sB, buf, tid, wv, lane);
            if (tid < DD) ws[W1_OFF + tid] = sB[0][tid];
            DOTB1(sB[0], BW1_OFF);
            rowcomb3(C, sB, sA, buf, tid, wv, lane);
            if (tid < DD) ws[P2_OFF + tid] = sA[0][tid];
        } else if (blk == 4) {   // p1 = u-comb C ; bu
            ZERO_A();
            if (tid < DD) sA[0][tid] = ws[UQWX_OFF + tid];
            __syncthreads();
            rowcomb3(C, sA, sB, buf, tid, wv, lane);
            if (tid < DD) ws[P1_OFF + tid] = sB[0][tid];
            DOTB1(sA[0], BU_OFF);
        } else {                 // w2 = u-comb X2
            ZERO_A();
            if (tid < DD) sA[0][tid] = ws[UQWX_OFF + tid];
            __syncthreads();
            rowcomb3(X2, sA, sB, buf, tid, wv, lane);
            if (tid < DD) ws[W2_OFF + tid] = sB[0][tid];
        }
        return;
    }

    // ---- EU + E16 tables ----
    if (tid < DD) u_s[tid] = ws[U_OFF + tid];
    __syncthreads();

    const float4* u4 = (const float4*)u_s;
    const float4  q0 = u4[lane];
    const float4  q1 = (lane < 11) ? u4[64 + lane] : float4{0, 0, 0, 0};
    ushort4* e16 = (ushort4*)(ws + E16_OFF);

    const int gw     = (blk - 6) * 16 + wv;
    const int stride = (gridDim.x - 6) * 16;
    for (int v = gw; v < VV; v += stride) {
        const float4* er = (const float4*)(emb + (size_t)v * DD);
        const float4 e0 = er[lane];
        float4 e1{0, 0, 0, 0};
        float a = e0.x * q0.x + e0.y * q0.y + e0.z * q0.z + e0.w * q0.w;
        if (lane < 11) {
            e1 = er[64 + lane];
            a += e1.x * q1.x + e1.y * q1.y + e1.z * q1.z + e1.w * q1.w;
        }
        a = wred(a);
        if (lane == 0) ws[EU_OFF + v] = a;
        if (do16) {
            ushort4 h0;
            h0.x = __half_as_ushort(__float2half(e0.x));
            h0.y = __half_as_ushort(__float2half(e0.y));
            h0.z = __half_as_ushort(__float2half(e0.z));
            h0.w = __half_as_ushort(__float2half(e0.w));
            e16[(size_t)v * NF4 + lane] = h0;
            if (lane < 11) {
                ushort4 h1;
                h1.x = __half_as_ushort(__float2half(e1.x));
                h1.y = __half_as_ushort(__float2half(e1.y));
                h1.z = __half_as_ushort(__float2half(e1.z));
                h1.w = __half_as_ushort(__float2half(e1.w));
                e16[(size_t)v * NF4 + 64 + lane] = h1;
            }
        }
    }
}

// ---------------------------------------------------------------------------
// k_hops: 256 blocks x 1024 threads, 2 batch rows per block. Full per-row
// pipeline in LDS. Per-hop 300x300 GEMVs replaced by dot products against
// precomposed vectors (p1,p2,w1,w2) and 3x300 matrices (D0..D3):
//   qs_1 = isp1*(m1.p1) + X0.w1 + B.u + cqs
//   qs_2 = isp2*(m2.p1) + isp1*(m1.p2) + X0.w2 + B.w1 + B.u + cqs
//   out  = sum_h isp_h*(m_h.D_h) + D0@X0 + (Wd+F1+F2)@B + bd
// ---------------------------------------------------------------------------
__global__ __launch_bounds__(1024) void k_hops(
    const int* __restrict__ text, const int* __restrict__ asp,
    const float* __restrict__ emb, float* __restrict__ out,
    float* __restrict__ ws, const int use16)
{
    const int b0   = blockIdx.x * 2;
    const int tid  = threadIdx.x;
    const int wv   = tid >> 6;     // 0..15
    const int lane = tid & 63;
    const int bb   = tid >> 9;     // row within pair (0/1)
    const int s    = tid & 511;    // sequence position

    __shared__ int   stok[2][512];
    __shared__ float ksA [2][512];
    __shared__ float cw  [2][512];
    __shared__ __align__(16) float mpart[16][304];
    __shared__ __align__(16) float X0[2][304];
    __shared__ float red[16];
    __shared__ float redm[2][5][8];
    __shared__ float qsv[2], ispv[2], aw1v[2], aw2v[2], d12v[2];
    __shared__ float oaccs[2][3];
    __shared__ int   s0v[2], lenv[2], nw0s;

    const float ck  = ws[CK];
    const float cqs = ws[CQS];
    const float bu  = ws[BU_OFF];
    const float bw1 = ws[BW1_OFF];

    // ---- init: tokens + len + X0 ----
    const int t = text[(b0 + bb) * SS + s];
    stok[bb][s] = t;
    {
        const unsigned long long bal = __ballot(t != 0);
        if (lane == 0) red[wv] = (float)__popcll(bal);
    }
    if (tid < 608) {
        const int ab = tid / 304, i2 = tid - ab * 304;
        if (i2 < DD) {
            float na = 0.f, a = 0.f;
            #pragma unroll
            for (int k = 0; k < 8; ++k) {
                const int idx = asp[(b0 + ab) * 8 + k];
                na += (idx != 0) ? 1.0f : 0.0f;
                a += emb[(size_t)idx * DD + i2];
            }
            X0[ab][i2] = a / na;
        }
    }
    __syncthreads();
    if (tid < 2) {
        int len = 0;
        #pragma unroll
        for (int w = 0; w < 8; ++w) len += (int)red[tid * 8 + w];
        lenv[tid] = len;
        s0v[tid]  = SS - len;
    }
    __syncthreads();
    if (tid == 0) {
        const int l0 = lenv[0], l1 = lenv[1];
        nw0s = min(15, max(1, (16 * l0) / (l0 + l1)));
    }
    // ks row (hop-invariant)
    {
        const int j = s - s0v[bb];
        const float wg = (j >= 0) ? (1.0f - (float)j / (float)lenv[bb]) : 1.0f;
        ksA[bb][s] = wg * ws[EU_OFF + t] + ck;
    }
    // init dots: X0.u, X0.w1, X0.w2, D0@X0
    {
        const int r = bb, j = s;
        const int wvr = wv - r * 8;
        if (wvr < 5) {
            const bool a = (j < DD);
            const float x = a ? X0[r][j] : 0.f;
            float v0 = a ? x * ws[UQWX_OFF + j] : 0.f;
            float v1 = a ? x * ws[W1_OFF + j] : 0.f;
            float v2 = a ? x * ws[W2_OFF + j] : 0.f;
            float v3 = a ? x * ws[D0_OFF + j] : 0.f;
            float v4 = a ? x * ws[D0_OFF + DD + j] : 0.f;
            float v5 = a ? x * ws[D0_OFF + 2 * DD + j] : 0.f;
            v0 = wred(v0); v1 = wred(v1); v2 = wred(v2);
            v3 = wred(v3); v4 = wred(v4); v5 = wred(v5);
            if (lane == 0) {
                redm[r][wvr][0] = v0; redm[r][wvr][1] = v1;
                redm[r][wvr][2] = v2; redm[r][wvr][3] = v3;
                redm[r][wvr][4] = v4; redm[r][wvr][5] = v5;
            }
        }
    }
    __syncthreads();
    if ((tid & 511) == 0) {
        const int r = bb;
        float s0_ = 0, s1_ = 0, s2_ = 0, s3_ = 0, s4_ = 0, s5_ = 0;
        #pragma unroll
        for (int w = 0; w < 5; ++w) {
            s0_ += redm[r][w][0]; s1_ += redm[r][w][1]; s2_ += redm[r][w][2];
            s3_ += redm[r][w][3]; s4_ += redm[r][w][4]; s5_ += redm[r][w][5];
        }
        qsv[r]  = s0_ + cqs;
        aw1v[r] = s1_;
        aw2v[r] = s2_;
        oaccs[r][0] = s3_ + ws[C3A_OFF + 0] + ws[C3B_OFF + 0] + ws[C3C_OFF + 0];
        oaccs[r][1] = s4_ + ws[C3A_OFF + 1] + ws[C3B_OFF + 1] + ws[C3C_OFF + 1];
        oaccs[r][2] = s5_ + ws[C3A_OFF + 2] + ws[C3B_OFF + 2] + ws[C3C_OFF + 2];
    }

    // ---- 3 hops ----
    for (int h = 0; h < 3; ++h) {
        __syncthreads();   // qsv/oaccs stable; mpart free
        // scores
        {
            const float qs = qsv[bb];
            const int s0 = s0v[bb];
            float p = 0.f;
            if (s >= s0) {
                p = fast_exp_tanh(ksA[bb][s] + qs);
                cw[bb][s] = p * (1.0f - (float)(s - s0) / (float)lenv[bb]);
            }
            p = wred(p);
            if (lane == 0) red[wv] = p;
        }
        __syncthreads();
        if (tid < 2) {
            float sp = 0.f;
            #pragma unroll
            for (int w = 0; w < 8; ++w) sp += red[tid * 8 + w];
            const int s0 = s0v[tid];
            if (s0 > 0) sp += (float)s0 * fast_exp_tanh(ck + qsv[tid]);
            ispv[tid] = 1.0f / sp;
        }
        // gather: waves split proportionally to row lengths
        {
            const int nw0 = nw0s;
            const int rb  = (wv < nw0) ? 0 : 1;
            const int wi  = rb ? (wv - nw0) : wv;
            const int nch = rb ? (16 - nw0) : nw0;
            const int s0  = s0v[rb];
            const int q   = (lenv[rb] + nch - 1) / nch;
            const int sb  = s0 + wi * q;
            const int se  = min(sb + q, SS);
            float4 acc{0, 0, 0, 0}, accb{0, 0, 0, 0};
            if (sb < se) {
                if (use16) {
                    const ushort4* e16 = (const ushort4*)(ws + E16_OFF);
                    ushort4 ca[4] = {}, cb[4] = {};
                    #pragma unroll
                    for (int k = 0; k < 4; ++k) {
                        const int rr = sb + k;
                        if (rr < se) {
                            const ushort4* rp = e16 + (size_t)stok[rb][rr] * NF4;
                            ca[k] = rp[lane];
                            if (lane < 11) cb[k] = rp[64 + lane];
                        }
                    }
                    for (int base = sb; base < se; base += 4) {
                        ushort4 na[4] = {}, nb[4] = {};
                        #pragma unroll
                        for (int k = 0; k < 4; ++k) {
                            const int rn = base + 4 + k;
                            if (rn < se) {
                                const ushort4* rp = e16 + (size_t)stok[rb][rn] * NF4;
                                na[k] = rp[lane];
                                if (lane < 11) nb[k] = rp[64 + lane];
                            }
                        }
                        #pragma unroll
                        for (int k = 0; k < 4; ++k) {
                            const int rr = base + k;
                            if (rr < se) {
                                const float cc = cw[rb][rr];
                                const float2 f0 = __half22float2(*(const __half2*)&ca[k].x);
                                const float2 f1 = __half22float2(*(const __half2*)&ca[k].z);
                                acc.x += cc * f0.x; acc.y += cc * f0.y;
                                acc.z += cc * f1.x; acc.w += cc * f1.y;
                                if (lane < 11) {
                                    const float2 g0 = __half22float2(*(const __half2*)&cb[k].x);
                                    const float2 g1 = __half22float2(*(const __half2*)&cb[k].z);
                                    accb.x += cc * g0.x; accb.y += cc * g0.y;
                                    accb.z += cc * g1.x; accb.w += cc * g1.y;
                                }
                            }
                        }
                        #pragma unroll
                        for (int k = 0; k < 4; ++k) { ca[k] = na[k]; cb[k] = nb[k]; }
                    }
                } else {
                    for (int rr = sb; rr < se; ++rr) {
                        const float cc = cw[rb][rr];
                        const float4* er = (const float4*)(emb + (size_t)stok[rb][rr] * DD);
                        const float4 f = er[lane];
                        acc.x += cc * f.x; acc.y += cc * f.y;
                        acc.z += cc * f.z; acc.w += cc * f.w;
                        if (lane < 11) {
                            const float4 f1 = er[64 + lane];
                            accb.x += cc * f1.x; accb.y += cc * f1.y;
                            accb.z += cc * f1.z; accb.w += cc * f1.w;
                        }
                    }
                }
            }
            ((float4*)&mpart[wv][0])[lane] = acc;
            if (lane < 11) ((float4*)&mpart[wv][0])[64 + lane] = accb;
        }
        __syncthreads();
        // dots on raw m
        {
            const int r = bb, j = s;
            const int wvr = wv - r * 8;
            if (wvr < 5) {
                const bool a = (j < DD);
                float m = 0.f;
                if (a) {
                    const int w0  = r ? nw0s : 0;
                    const int w1e = r ? 16 : nw0s;
                    for (int w = w0; w < w1e; ++w) m += mpart[w][j];
                }
                float v0 = 0, v1 = 0, v2 = 0, v3 = 0, v4 = 0;
                if (a) {
                    if (h == 0) {
                        v0 = m * ws[P1_OFF + j];
                        v1 = m * ws[P2_OFF + j];
                        v2 = m * ws[D1_OFF + j];
                        v3 = m * ws[D1_OFF + DD + j];
                        v4 = m * ws[D1_OFF + 2 * DD + j];
                    } else if (h == 1) {
                        v0 = m * ws[P1_OFF + j];
                        v2 = m * ws[D2_OFF + j];
                        v3 = m * ws[D2_OFF + DD + j];
                        v4 = m * ws[D2_OFF + 2 * DD + j];
                    } else {
                        v2 = m * ws[D3_OFF + j];
                        v3 = m * ws[D3_OFF + DD + j];
                        v4 = m * ws[D3_OFF + 2 * DD + j];
                    }
                }
                v0 = wred(v0); v1 = wred(v1); v2 = wred(v2);
                v3 = wred(v3); v4 = wred(v4);
                if (lane == 0) {
                    redm[r][wvr][0] = v0; redm[r][wvr][1] = v1;
                    redm[r][wvr][2] = v2; redm[r][wvr][3] = v3;
                    redm[r][wvr][4] = v4;
                }
            }
        }
        __syncthreads();
        if ((tid & 511) == 0) {
            const int r = bb;
            float s0_ = 0, s1_ = 0, s2_ = 0, s3_ = 0, s4_ = 0;
            #pragma unroll
            for (int w = 0; w < 5; ++w) {
                s0_ += redm[r][w][0]; s1_ += redm[r][w][1];
                s2_ += redm[r][w][2]; s3_ += redm[r][w][3];
                s4_ += redm[r][w][4];
            }
            const float isp = ispv[r];
            if (h == 0) {
                qsv[r]  = s0_ * isp + aw1v[r] + bu + cqs;
                d12v[r] = s1_ * isp;
                oaccs[r][0] += s2_ * isp;
                oaccs[r][1] += s3_ * isp;
                oaccs[r][2] += s4_ * isp;
            } else if (h == 1) {
                qsv[r] = s0_ * isp + d12v[r] + aw2v[r] + bw1 + bu + cqs;
                oaccs[r][0] += s2_ * isp;
                oaccs[r][1] += s3_ * isp;
                oaccs[r][2] += s4_ * isp;
            } else {
                out[(b0 + r) * 3 + 0] = oaccs[r][0] + s2_ * isp;
                out[(b0 + r) * 3 + 1] = oaccs[r][1] + s3_ * isp;
                out[(b0 + r) * 3 + 2] = oaccs[r][2] + s4_ * isp;
            }
        }
    }
}

extern "C" void kernel_launch(void* const* d_in, const int* in_sizes, int n_in,
                              void* d_out, int out_size, void* d_ws, size_t ws_size,
                              hipStream_t stream)
{
    const int*   text = (const int*)d_in[0];
    const int*   asp  = (const int*)d_in[1];
    const float* emb  = (const float*)d_in[2];
    const float* Wx   = (const float*)d_in[3];
    const float* bx   = (const float*)d_in[4];
    const float* Wk   = (const float*)d_in[5];
    const float* bk   = (const float*)d_in[6];
    const float* Wq   = (const float*)d_in[7];
    const float* bq   = (const float*)d_in[8];
    const float* wm   = (const float*)d_in[9];
    const float* Wp   = (const float*)d_in[10];
    const float* bp   = (const float*)d_in[11];
    const float* Wd   = (const float*)d_in[12];
    const float* bd   = (const float*)d_in[13];
    float* out = (float*)d_out;
    float* ws  = (float*)d_ws;

    const size_t need = (size_t)E16_OFF * 4 + (size_t)VV * DD * 2;
    const int use16 = (ws_size >= need) ? 1 : 0;

    pre<<<203, 1024, 0, stream>>>(Wk, bk, Wq, bq, wm, Wp, bp, Wx, bx, ws);
    build_tables<<<518, 1024, 0, stream>>>(emb, Wx, Wp, Wk, Wd, bd, ws, use16);
    k_hops<<<256, 1024, 0, stream>>>(text, asp, emb, out, ws, use16);
}

// Round 3
// 210.235 us; speedup vs baseline: 1.2633x; 1.0914x over previous
//
#include <hip/hip_runtime.h>
#include <hip/hip_fp16.h>

#define DD 300
#define SS 512
#define VV 50000

// Workspace layout (float index):
#define CK       0
#define CQS      1
#define BU       2        // B·u
#define BW1      3        // B·w1
#define C3A      4        // F1@B (3)
#define C3B      8        // F2@B (3)
#define C3C      12       // Wd@B + bd (3)
#define U_OFF    16       // u_emb = wk@Wk (300)   [for eu]
#define UQWX_OFF 320      // u  = Wx^T@uq (300)
#define W1_OFF   640      // w1 = Wx^T@u
#define W2_OFF   960      // w2 = (Wx^2)^T@u
#define D0_OFF   1280     // Wd@Wx^3 (3x300)
#define P1_OFF   2240     // C^T@u   (C = Wp@Wk)
#define P2_OFF   2560     // C^T@w1
#define D1_OFF   2880     // (Wd@Wx^2)@C (3x300)
#define D2_OFF   3840     // (Wd@Wx)@C   (3x300)
#define D3_OFF   4800     // Wd@C        (3x300)
#define TAB_OFF  8192     // tab[v][12] = e_v·{p1,p2,D1r0..2,D2r0..2,D3r0..2,u_emb}

#define FMA4(acc, s, v) { acc.x += (s)*(v).x; acc.y += (s)*(v).y; \
                          acc.z += (s)*(v).z; acc.w += (s)*(v).w; }

__device__ __forceinline__ float fast_exp_tanh(float z) {
    const float t = __expf(2.0f * z);
    return __expf(1.0f - 2.0f / (t + 1.0f));
}

__device__ __forceinline__ float wred(float v) {
    #pragma unroll
    for (int off = 32; off; off >>= 1) v += __shfl_xor(v, off);
    return v;
}

// ---------------------------------------------------------------------------
// vcomb: sOut[j] = sum_i sIn[i] * M[i,j]  (vector x row-major 300x300).
// 1024 threads, internal barriers (trailing barrier included).
// ---------------------------------------------------------------------------
__device__ __forceinline__ void vcomb(
    const float* __restrict__ M, const float* __restrict__ sIn,
    float* __restrict__ sOut, float* __restrict__ buf,
    const int tid, const int wv, const int lane)
{
    float4 a0{0,0,0,0}, a1{0,0,0,0};
    for (int e = wv; e < DD; e += 16) {
        const float4* kr = (const float4*)(M + e * DD);
        const float s = sIn[e];
        FMA4(a0, s, kr[lane]);
        if (lane < 11) { const float4 k1 = kr[64 + lane]; FMA4(a1, s, k1); }
    }
    float4* pr = (float4*)(buf + wv * 304);
    pr[lane] = a0;
    if (lane < 11) pr[64 + lane] = a1;
    __syncthreads();
    if (tid < DD) {
        float s = 0.f;
        #pragma unroll
        for (int w = 0; w < 16; ++w) s += buf[w * 304 + tid];
        sOut[tid] = s;
    }
    __syncthreads();
}

// ---------------------------------------------------------------------------
// rowcomb3: sOut[r][:] = sum_i sIn[r][i] * M[i,:]  (3 rows at once).
// ---------------------------------------------------------------------------
__device__ __forceinline__ void rowcomb3(
    const float* __restrict__ M, const float (*sIn)[304], float (*sOut)[304],
    float* __restrict__ buf, const int tid, const int wv, const int lane)
{
    float4 a00{0,0,0,0}, a01{0,0,0,0}, a10{0,0,0,0},
           a11{0,0,0,0}, a20{0,0,0,0}, a21{0,0,0,0};
    for (int e = wv; e < DD; e += 16) {
        const float4* kr = (const float4*)(M + e * DD);
        const float4 k0 = kr[lane];
        const float p0 = sIn[0][e], p1 = sIn[1][e], p2 = sIn[2][e];
        FMA4(a00, p0, k0); FMA4(a10, p1, k0); FMA4(a20, p2, k0);
        if (lane < 11) {
            const float4 k1 = kr[64 + lane];
            FMA4(a01, p0, k1); FMA4(a11, p1, k1); FMA4(a21, p2, k1);
        }
    }
    float4* p0r = (float4*)(buf + (wv * 3 + 0) * 304);
    float4* p1r = (float4*)(buf + (wv * 3 + 1) * 304);
    float4* p2r = (float4*)(buf + (wv * 3 + 2) * 304);
    p0r[lane] = a00; p1r[lane] = a10; p2r[lane] = a20;
    if (lane < 11) { p0r[64+lane] = a01; p1r[64+lane] = a11; p2r[64+lane] = a21; }
    __syncthreads();
    if (tid < DD) {
        #pragma unroll
        for (int r = 0; r < 3; ++r) {
            float s = 0.f;
            for (int w = 0; w < 16; ++w) s += buf[(w * 3 + r) * 304 + tid];
            sOut[r][tid] = s;
        }
    }
    __syncthreads();
}

// ---------------------------------------------------------------------------
// bpass: sB[i] = Wp[i,:]·sbk + bp[i] + bx[i]  (row dots, trailing barrier).
// ---------------------------------------------------------------------------
__device__ __forceinline__ void bpass(
    const float* __restrict__ Wp, const float* __restrict__ bp,
    const float* __restrict__ bx, const float* __restrict__ sbk,
    float* __restrict__ sB, const int wv, const int lane)
{
    const float4* b4 = (const float4*)sbk;
    const float4 k0 = b4[lane];
    const float4 k1 = (lane < 11) ? b4[64 + lane] : float4{0, 0, 0, 0};
    for (int i2 = wv; i2 < DD; i2 += 16) {
        const float4* wr = (const float4*)(Wp + i2 * DD);
        const float4 w0 = wr[lane];
        float a = w0.x * k0.x + w0.y * k0.y + w0.z * k0.z + w0.w * k0.w;
        if (lane < 11) {
            const float4 w1 = wr[64 + lane];
            a += w1.x * k1.x + w1.y * k1.y + w1.z * k1.z + w1.w * k1.w;
        }
        a = wred(a);
        if (lane == 0) sB[i2] = a + bp[i2] + bx[i2];
    }
    __syncthreads();
}

// ---------------------------------------------------------------------------
// pre: 8 blocks x 1024. All composed vectors / 3x300 matrices directly from
// raw Wx/Wp/Wk/Wq/Wd chains (no C / Wx^2 materialization).
//   0: u_emb = wk@Wk ; ck
//   1: uq,u,w1,w2 ; cqs ; B ; bu,bw1
//   2: p1 = Wk^T Wp^T u
//   3: p2 = Wk^T Wp^T w1
//   4: A2=WdWx, A3=WdWx^2, D0=WdWx^3 ; B ; c3a,c3b,c3c
//   5: D3 = Wd Wp Wk
//   6: D2 = Wd Wx Wp Wk
//   7: D1 = Wd Wx^2 Wp Wk
// ---------------------------------------------------------------------------
__global__ __launch_bounds__(1024) void pre(
    const float* __restrict__ Wk, const float* __restrict__ bk,
    const float* __restrict__ Wq, const float* __restrict__ bq,
    const float* __restrict__ w_mlp,
    const float* __restrict__ Wp, const float* __restrict__ bp,
    const float* __restrict__ Wx, const float* __restrict__ bx,
    const float* __restrict__ Wd, const float* __restrict__ bd,
    float* __restrict__ ws)
{
    const int blk  = blockIdx.x;
    const int tid  = threadIdx.x;
    const int wv   = tid >> 6;
    const int lane = tid & 63;
    __shared__ __align__(16) float buf[16 * 304 * 3];
    __shared__ __align__(16) float v0[304], v1[304], v2[304], v3[304], v4[304], vB[304];
    __shared__ __align__(16) float m0[3][304], m1[3][304], mW[3][304];

    if (blk == 0) {
        if (tid < DD) v0[tid] = w_mlp[tid];              // wk
        __syncthreads();
        vcomb(Wk, v0, v1, buf, tid, wv, lane);           // u_emb
        if (tid < DD) ws[U_OFF + tid] = v1[tid];
        if (wv == 0) {
            float c = 0.f;
            for (int j = lane; j < DD; j += 64) c += v0[j] * bk[j];
            c = wred(c);
            if (lane == 0) ws[CK] = c;
        }
        return;
    }

    if (blk == 1) {
        if (tid < DD) v0[tid] = w_mlp[DD + tid];         // wq
        __syncthreads();
        vcomb(Wq, v0, v1, buf, tid, wv, lane);           // uq
        vcomb(Wx, v1, v2, buf, tid, wv, lane);           // u
        vcomb(Wx, v2, v3, buf, tid, wv, lane);           // w1
        vcomb(Wx, v3, v4, buf, tid, wv, lane);           // w2
        if (tid < DD) {
            ws[UQWX_OFF + tid] = v2[tid];
            ws[W1_OFF + tid]   = v3[tid];
            ws[W2_OFF + tid]   = v4[tid];
        }
        if (wv == 0) {                                    // cqs = wq·bq + uq·bx
            float c = 0.f;
            for (int j = lane; j < DD; j += 64) c += v0[j] * bq[j] + v1[j] * bx[j];
            c = wred(c);
            if (lane == 0) ws[CQS] = c;
        }
        __syncthreads();
        if (tid < DD) v1[tid] = bk[tid];
        __syncthreads();
        bpass(Wp, bp, bx, v1, vB, wv, lane);             // B
        if (wv == 0) {
            float a = 0.f, b = 0.f;
            for (int j = lane; j < DD; j += 64) { a += vB[j] * v2[j]; b += vB[j] * v3[j]; }
            a = wred(a); b = wred(b);
            if (lane == 0) { ws[BU] = a; ws[BW1] = b; }
        }
        return;
    }

    if (blk == 2 || blk == 3) {
        if (tid < DD) v0[tid] = w_mlp[DD + tid];         // wq
        __syncthreads();
        vcomb(Wq, v0, v1, buf, tid, wv, lane);           // uq
        vcomb(Wx, v1, v2, buf, tid, wv, lane);           // u
        if (blk == 2) {
            vcomb(Wp, v2, v3, buf, tid, wv, lane);
            vcomb(Wk, v3, v4, buf, tid, wv, lane);       // p1
            if (tid < DD) ws[P1_OFF + tid] = v4[tid];
        } else {
            vcomb(Wx, v2, v3, buf, tid, wv, lane);       // w1
            vcomb(Wp, v3, v4, buf, tid, wv, lane);
            vcomb(Wk, v4, v0, buf, tid, wv, lane);       // p2
            if (tid < DD) ws[P2_OFF + tid] = v0[tid];
        }
        return;
    }

    // blocks 4..7 start from Wd rows
    for (int r = tid; r < 3 * DD; r += 1024) mW[r / DD][r % DD] = Wd[r];
    __syncthreads();

    if (blk == 4) {
        rowcomb3(Wx, mW, m0, buf, tid, wv, lane);        // A2 = Wd@Wx
        rowcomb3(Wx, m0, m1, buf, tid, wv, lane);        // A3 = Wd@Wx^2
        if (tid < DD) v1[tid] = bk[tid];
        __syncthreads();
        bpass(Wp, bp, bx, v1, vB, wv, lane);             // B
        if (wv < 3) {
            float ca = 0.f, cb = 0.f, cc = 0.f;
            for (int j = lane; j < DD; j += 64) {
                const float b = vB[j];
                ca += m0[wv][j] * b; cb += m1[wv][j] * b; cc += mW[wv][j] * b;
            }
            ca = wred(ca); cb = wred(cb); cc = wred(cc);
            if (lane == 0) {
                ws[C3A + wv] = ca;
                ws[C3B + wv] = cb;
                ws[C3C + wv] = cc + bd[wv];
            }
        }
        rowcomb3(Wx, m1, m0, buf, tid, wv, lane);        // D0 = Wd@Wx^3
        for (int r = tid; r < 3 * DD; r += 1024) ws[D0_OFF + r] = m0[r / DD][r % DD];
        return;
    }
    if (blk == 5) {
        rowcomb3(Wp, mW, m0, buf, tid, wv, lane);
        rowcomb3(Wk, m0, m1, buf, tid, wv, lane);        // D3
        for (int r = tid; r < 3 * DD; r += 1024) ws[D3_OFF + r] = m1[r / DD][r % DD];
        return;
    }
    if (blk == 6) {
        rowcomb3(Wx, mW, m0, buf, tid, wv, lane);
        rowcomb3(Wp, m0, m1, buf, tid, wv, lane);
        rowcomb3(Wk, m1, m0, buf, tid, wv, lane);        // D2
        for (int r = tid; r < 3 * DD; r += 1024) ws[D2_OFF + r] = m0[r / DD][r % DD];
        return;
    }
    {   // blk 7
        rowcomb3(Wx, mW, m0, buf, tid, wv, lane);
        rowcomb3(Wx, m0, m1, buf, tid, wv, lane);
        rowcomb3(Wp, m1, m0, buf, tid, wv, lane);
        rowcomb3(Wk, m0, m1, buf, tid, wv, lane);        // D1
        for (int r = tid; r < 3 * DD; r += 1024) ws[D1_OFF + r] = m1[r / DD][r % DD];
    }
}

// ---------------------------------------------------------------------------
// build_tables: 512 blocks x 1024. tab[v][0..11] = emb[v]·{p1,p2,D1r0..2,
// D2r0..2,D3r0..2,u_emb}. Pure 60 MB stream; 2.4 MB table (L2-resident).
// ---------------------------------------------------------------------------
__global__ __launch_bounds__(1024) void build_tables(
    const float* __restrict__ emb, float* __restrict__ ws)
{
    const int tid  = threadIdx.x;
    const int wv   = tid >> 6;
    const int lane = tid & 63;
    __shared__ __align__(16) float sV[12][304];

    if (tid < DD) {
        const int j = tid;
        sV[0][j]  = ws[P1_OFF + j];
        sV[1][j]  = ws[P2_OFF + j];
        sV[2][j]  = ws[D1_OFF + j];
        sV[3][j]  = ws[D1_OFF + DD + j];
        sV[4][j]  = ws[D1_OFF + 2 * DD + j];
        sV[5][j]  = ws[D2_OFF + j];
        sV[6][j]  = ws[D2_OFF + DD + j];
        sV[7][j]  = ws[D2_OFF + 2 * DD + j];
        sV[8][j]  = ws[D3_OFF + j];
        sV[9][j]  = ws[D3_OFF + DD + j];
        sV[10][j] = ws[D3_OFF + 2 * DD + j];
        sV[11][j] = ws[U_OFF + j];
    }
    __syncthreads();

    float* tab = ws + TAB_OFF;
    const int gw     = blockIdx.x * 16 + wv;
    const int stride = gridDim.x * 16;
    for (int v = gw; v < VV; v += stride) {
        const float4* er = (const float4*)(emb + (size_t)v * DD);
        const float4 e0 = er[lane];
        float4 e1{0, 0, 0, 0};
        if (lane < 11) e1 = er[64 + lane];
        float r[12];
        #pragma unroll
        for (int k = 0; k < 12; ++k) {
            const float4* v4 = (const float4*)sV[k];
            const float4 a = v4[lane];
            float acc = e0.x * a.x + e0.y * a.y + e0.z * a.z + e0.w * a.w;
            if (lane < 11) {
                const float4 b = v4[64 + lane];
                acc += e1.x * b.x + e1.y * b.y + e1.z * b.z + e1.w * b.w;
            }
            r[k] = wred(acc);
        }
        if (lane == 0) {
            float4* tp = (float4*)(tab + (size_t)v * 12);
            tp[0] = float4{r[0], r[1], r[2],  r[3]};
            tp[1] = float4{r[4], r[5], r[6],  r[7]};
            tp[2] = float4{r[8], r[9], r[10], r[11]};
        }
    }
}

// ---------------------------------------------------------------------------
// k_hops: 512 blocks x 512 threads, 1 batch row per block. No embedding
// gathers: per-token 48B tab row, all hop math is scalars + wave reductions.
// ---------------------------------------------------------------------------
__global__ __launch_bounds__(512) void k_hops(
    const int* __restrict__ text, const int* __restrict__ asp,
    const float* __restrict__ emb, float* __restrict__ out,
    const float* __restrict__ ws)
{
    const int b    = blockIdx.x;
    const int tid  = threadIdx.x;
    const int wv   = tid >> 6;     // 0..7
    const int lane = tid & 63;

    __shared__ __align__(16) float X0s[304];
    __shared__ float rlen[8];
    __shared__ float rp[8][6];
    __shared__ float qsv;

    const float ck  = ws[CK];
    const float cqs = ws[CQS];

    const int t = text[b * SS + tid];
    {
        const unsigned long long bal = __ballot(t != 0);
        if (lane == 0) rlen[wv] = (float)__popcll(bal);
    }
    const float4* tr = (const float4*)(ws + TAB_OFF + (size_t)t * 12);
    const float4 tA = tr[0];
    const float4 tB = tr[1];
    const float4 tC = tr[2];

    if (tid < DD) {
        float na = 0.f, a = 0.f;
        #pragma unroll
        for (int k = 0; k < 8; ++k) {
            const int idx = asp[b * 8 + k];
            na += (idx != 0) ? 1.0f : 0.0f;
            a += emb[(size_t)idx * DD + tid];
        }
        X0s[tid] = a / na;
    }
    __syncthreads();

    float lenf; int s0;
    {
        float l = 0.f;
        #pragma unroll
        for (int w = 0; w < 8; ++w) l += rlen[w];
        lenf = l; s0 = SS - (int)l;
    }
    const bool act = (tid >= s0);
    const float wg  = act ? (1.0f - (float)(tid - s0) / lenf) : 0.f;
    const float ksr = wg * tC.w + ck;            // eu = tC.w

    // init dots (wave 0): X0·u, X0·w1, X0·w2, D0@X0
    float aw1 = 0.f, aw2 = 0.f, d12 = 0.f, o0 = 0.f, o1 = 0.f, o2 = 0.f;
    if (wv == 0) {
        float pq = 0.f, p1 = 0.f, p2 = 0.f, pd0 = 0.f, pd1 = 0.f, pd2 = 0.f;
        for (int j = lane; j < DD; j += 64) {
            const float x = X0s[j];
            pq  += x * ws[UQWX_OFF + j];
            p1  += x * ws[W1_OFF + j];
            p2  += x * ws[W2_OFF + j];
            pd0 += x * ws[D0_OFF + j];
            pd1 += x * ws[D0_OFF + DD + j];
            pd2 += x * ws[D0_OFF + 2 * DD + j];
        }
        pq = wred(pq); aw1 = wred(p1); aw2 = wred(p2);
        o0 = wred(pd0) + ws[C3A + 0] + ws[C3B + 0] + ws[C3C + 0];
        o1 = wred(pd1) + ws[C3A + 1] + ws[C3B + 1] + ws[C3C + 1];
        o2 = wred(pd2) + ws[C3A + 2] + ws[C3B + 2] + ws[C3C + 2];
        if (lane == 0) qsv = pq + cqs;
    }
    __syncthreads();

    const float bu = ws[BU], bw1 = ws[BW1];

    #pragma unroll
    for (int h = 0; h < 3; ++h) {
        const float qs = qsv;
        float p = 0.f;
        if (act) p = fast_exp_tanh(ksr + qs);
        const float pw = p * wg;
        float u0 = p, u1, u2, u3, u4 = 0.f, u5 = 0.f;
        if (h == 0)      { u1 = pw*tA.x; u2 = pw*tA.y; u3 = pw*tA.z; u4 = pw*tA.w; u5 = pw*tB.x; }
        else if (h == 1) { u1 = pw*tA.x; u2 = pw*tB.y; u3 = pw*tB.z; u4 = pw*tB.w; }
        else             { u1 = pw*tC.x; u2 = pw*tC.y; u3 = pw*tC.z; }
        u0 = wred(u0); u1 = wred(u1); u2 = wred(u2); u3 = wred(u3);
        if (h == 0) { u4 = wred(u4); u5 = wred(u5); }
        else if (h == 1) { u4 = wred(u4); }
        if (lane == 0) {
            rp[wv][0] = u0; rp[wv][1] = u1; rp[wv][2] = u2;
            rp[wv][3] = u3; rp[wv][4] = u4; rp[wv][5] = u5;
        }
        __syncthreads();
        if (wv == 0) {
            float s0_ = 0, s1_ = 0, s2_ = 0, s3_ = 0, s4_ = 0, s5_ = 0;
            #pragma unroll
            for (int w = 0; w < 8; ++w) {
                s0_ += rp[w][0]; s1_ += rp[w][1]; s2_ += rp[w][2];
                s3_ += rp[w][3]; s4_ += rp[w][4]; s5_ += rp[w][5];
            }
            const float sp  = s0_ + (float)s0 * fast_exp_tanh(ck + qs);
            const float isp = 1.0f / sp;
            if (h == 0) {
                d12 = isp * s2_;
                o0 += isp * s3_; o1 += isp * s4_; o2 += isp * s5_;
                if (lane == 0) qsv = isp * s1_ + aw1 + bu + cqs;
            } else if (h == 1) {
                o0 += isp * s2_; o1 += isp * s3_; o2 += isp * s4_;
                if (lane == 0) qsv = isp * s1_ + d12 + aw2 + bw1 + bu + cqs;
            } else if (lane == 0) {
                out[b * 3 + 0] = o0 + isp * s1_;
                out[b * 3 + 1] = o1 + isp * s2_;
                out[b * 3 + 2] = o2 + isp * s3_;
            }
        }
        if (h < 2) __syncthreads();
    }
}

extern "C" void kernel_launch(void* const* d_in, const int* in_sizes, int n_in,
                              void* d_out, int out_size, void* d_ws, size_t ws_size,
                              hipStream_t stream)
{
    const int*   text = (const int*)d_in[0];
    const int*   asp  = (const int*)d_in[1];
    const float* emb  = (const float*)d_in[2];
    const float* Wx   = (const float*)d_in[3];
    const float* bx   = (const float*)d_in[4];
    const float* Wk   = (const float*)d_in[5];
    const float* bk   = (const float*)d_in[6];
    const float* Wq   = (const float*)d_in[7];
    const float* bq   = (const float*)d_in[8];
    const float* wm   = (const float*)d_in[9];
    const float* Wp   = (const float*)d_in[10];
    const float* bp   = (const float*)d_in[11];
    const float* Wd   = (const float*)d_in[12];
    const float* bd   = (const float*)d_in[13];
    float* out = (float*)d_out;
    float* ws  = (float*)d_ws;

    pre<<<8, 1024, 0, stream>>>(Wk, bk, Wq, bq, wm, Wp, bp, Wx, bx, Wd, bd, ws);
    build_tables<<<512, 1024, 0, stream>>>(emb, ws);
    k_hops<<<512, 512, 0, stream>>>(text, asp, emb, out, ws);
}

// Round 4
// 206.392 us; speedup vs baseline: 1.2868x; 1.0186x over previous
//
#include <hip/hip_runtime.h>
#include <hip/hip_fp16.h>

#define DD 300
#define SS 512
#define VV 50000

// Workspace layout (float index):
#define CK       0
#define CQS      1
#define BU       2        // B·u
#define BW1      3        // B·w1
#define C3A      4        // F1@B (3)
#define C3B      8        // F2@B (3)
#define C3C      12       // Wd@B + bd (3)
#define U_OFF    16       // u_emb = wk@Wk (300)   [for eu]
#define UQWX_OFF 320      // u  = Wx^T@uq (300)
#define W1_OFF   640      // w1 = Wx^T@u
#define W2_OFF   960      // w2 = (Wx^2)^T@u
#define D0_OFF   1280     // Wd@Wx^3 (3x300)
#define P1_OFF   2240     // C^T@u   (C = Wp@Wk)
#define P2_OFF   2560     // C^T@w1
#define D1_OFF   2880     // (Wd@Wx^2)@C (3x300)
#define D2_OFF   3840     // (Wd@Wx)@C   (3x300)
#define D3_OFF   4800     // Wd@C        (3x300)
#define TAB_OFF  8192     // tab[v][12] = e_v·{p1,p2,D1r0..2,D2r0..2,D3r0..2,u_emb}

#define FMA4(acc, s, v) { acc.x += (s)*(v).x; acc.y += (s)*(v).y; \
                          acc.z += (s)*(v).z; acc.w += (s)*(v).w; }

__device__ __forceinline__ float fast_exp_tanh(float z) {
    const float t = __expf(2.0f * z);
    return __expf(1.0f - 2.0f / (t + 1.0f));
}

__device__ __forceinline__ float wred(float v) {
    #pragma unroll
    for (int off = 32; off; off >>= 1) v += __shfl_xor(v, off);
    return v;
}

// ---------------------------------------------------------------------------
// vcomb: sOut[j] = sum_i sIn[i] * M[i,j]  (vector x row-major 300x300).
// 1024 threads, internal barriers (trailing barrier included).
// ---------------------------------------------------------------------------
__device__ __forceinline__ void vcomb(
    const float* __restrict__ M, const float* __restrict__ sIn,
    float* __restrict__ sOut, float* __restrict__ buf,
    const int tid, const int wv, const int lane)
{
    float4 a0{0,0,0,0}, a1{0,0,0,0};
    for (int e = wv; e < DD; e += 16) {
        const float4* kr = (const float4*)(M + e * DD);
        const float s = sIn[e];
        FMA4(a0, s, kr[lane]);
        if (lane < 11) { const float4 k1 = kr[64 + lane]; FMA4(a1, s, k1); }
    }
    float4* pr = (float4*)(buf + wv * 304);
    pr[lane] = a0;
    if (lane < 11) pr[64 + lane] = a1;
    __syncthreads();
    if (tid < DD) {
        float s = 0.f;
        #pragma unroll
        for (int w = 0; w < 16; ++w) s += buf[w * 304 + tid];
        sOut[tid] = s;
    }
    __syncthreads();
}

// ---------------------------------------------------------------------------
// rowcomb3: sOut[r][:] = sum_i sIn[r][i] * M[i,:]  (3 rows at once).
// ---------------------------------------------------------------------------
__device__ __forceinline__ void rowcomb3(
    const float* __restrict__ M, const float (*sIn)[304], float (*sOut)[304],
    float* __restrict__ buf, const int tid, const int wv, const int lane)
{
    float4 a00{0,0,0,0}, a01{0,0,0,0}, a10{0,0,0,0},
           a11{0,0,0,0}, a20{0,0,0,0}, a21{0,0,0,0};
    for (int e = wv; e < DD; e += 16) {
        const float4* kr = (const float4*)(M + e * DD);
        const float4 k0 = kr[lane];
        const float p0 = sIn[0][e], p1 = sIn[1][e], p2 = sIn[2][e];
        FMA4(a00, p0, k0); FMA4(a10, p1, k0); FMA4(a20, p2, k0);
        if (lane < 11) {
            const float4 k1 = kr[64 + lane];
            FMA4(a01, p0, k1); FMA4(a11, p1, k1); FMA4(a21, p2, k1);
        }
    }
    float4* p0r = (float4*)(buf + (wv * 3 + 0) * 304);
    float4* p1r = (float4*)(buf + (wv * 3 + 1) * 304);
    float4* p2r = (float4*)(buf + (wv * 3 + 2) * 304);
    p0r[lane] = a00; p1r[lane] = a10; p2r[lane] = a20;
    if (lane < 11) { p0r[64+lane] = a01; p1r[64+lane] = a11; p2r[64+lane] = a21; }
    __syncthreads();
    if (tid < DD) {
        #pragma unroll
        for (int r = 0; r < 3; ++r) {
            float s = 0.f;
            for (int w = 0; w < 16; ++w) s += buf[(w * 3 + r) * 304 + tid];
            sOut[r][tid] = s;
        }
    }
    __syncthreads();
}

// ---------------------------------------------------------------------------
// bpass: sB[i] = Wp[i,:]·sbk + bp[i] + bx[i]  (row dots, trailing barrier).
// ---------------------------------------------------------------------------
__device__ __forceinline__ void bpass(
    const float* __restrict__ Wp, const float* __restrict__ bp,
    const float* __restrict__ bx, const float* __restrict__ sbk,
    float* __restrict__ sB, const int wv, const int lane)
{
    const float4* b4 = (const float4*)sbk;
    const float4 k0 = b4[lane];
    const float4 k1 = (lane < 11) ? b4[64 + lane] : float4{0, 0, 0, 0};
    for (int i2 = wv; i2 < DD; i2 += 16) {
        const float4* wr = (const float4*)(Wp + i2 * DD);
        const float4 w0 = wr[lane];
        float a = w0.x * k0.x + w0.y * k0.y + w0.z * k0.z + w0.w * k0.w;
        if (lane < 11) {
            const float4 w1 = wr[64 + lane];
            a += w1.x * k1.x + w1.y * k1.y + w1.z * k1.z + w1.w * k1.w;
        }
        a = wred(a);
        if (lane == 0) sB[i2] = a + bp[i2] + bx[i2];
    }
    __syncthreads();
}

// ---------------------------------------------------------------------------
// pre: 8 blocks x 1024. All composed vectors / 3x300 matrices directly from
// raw Wx/Wp/Wk/Wq/Wd chains (no C / Wx^2 materialization).
// ---------------------------------------------------------------------------
__global__ __launch_bounds__(1024) void pre(
    const float* __restrict__ Wk, const float* __restrict__ bk,
    const float* __restrict__ Wq, const float* __restrict__ bq,
    const float* __restrict__ w_mlp,
    const float* __restrict__ Wp, const float* __restrict__ bp,
    const float* __restrict__ Wx, const float* __restrict__ bx,
    const float* __restrict__ Wd, const float* __restrict__ bd,
    float* __restrict__ ws)
{
    const int blk  = blockIdx.x;
    const int tid  = threadIdx.x;
    const int wv   = tid >> 6;
    const int lane = tid & 63;
    __shared__ __align__(16) float buf[16 * 304 * 3];
    __shared__ __align__(16) float v0[304], v1[304], v2[304], v3[304], v4[304], vB[304];
    __shared__ __align__(16) float m0[3][304], m1[3][304], mW[3][304];

    if (blk == 0) {
        if (tid < DD) v0[tid] = w_mlp[tid];              // wk
        __syncthreads();
        vcomb(Wk, v0, v1, buf, tid, wv, lane);           // u_emb
        if (tid < DD) ws[U_OFF + tid] = v1[tid];
        if (wv == 0) {
            float c = 0.f;
            for (int j = lane; j < DD; j += 64) c += v0[j] * bk[j];
            c = wred(c);
            if (lane == 0) ws[CK] = c;
        }
        return;
    }

    if (blk == 1) {
        if (tid < DD) v0[tid] = w_mlp[DD + tid];         // wq
        __syncthreads();
        vcomb(Wq, v0, v1, buf, tid, wv, lane);           // uq
        vcomb(Wx, v1, v2, buf, tid, wv, lane);           // u
        vcomb(Wx, v2, v3, buf, tid, wv, lane);           // w1
        vcomb(Wx, v3, v4, buf, tid, wv, lane);           // w2
        if (tid < DD) {
            ws[UQWX_OFF + tid] = v2[tid];
            ws[W1_OFF + tid]   = v3[tid];
            ws[W2_OFF + tid]   = v4[tid];
        }
        if (wv == 0) {                                    // cqs = wq·bq + uq·bx
            float c = 0.f;
            for (int j = lane; j < DD; j += 64) c += v0[j] * bq[j] + v1[j] * bx[j];
            c = wred(c);
            if (lane == 0) ws[CQS] = c;
        }
        __syncthreads();
        if (tid < DD) v1[tid] = bk[tid];
        __syncthreads();
        bpass(Wp, bp, bx, v1, vB, wv, lane);             // B
        if (wv == 0) {
            float a = 0.f, b = 0.f;
            for (int j = lane; j < DD; j += 64) { a += vB[j] * v2[j]; b += vB[j] * v3[j]; }
            a = wred(a); b = wred(b);
            if (lane == 0) { ws[BU] = a; ws[BW1] = b; }
        }
        return;
    }

    if (blk == 2 || blk == 3) {
        if (tid < DD) v0[tid] = w_mlp[DD + tid];         // wq
        __syncthreads();
        vcomb(Wq, v0, v1, buf, tid, wv, lane);           // uq
        vcomb(Wx, v1, v2, buf, tid, wv, lane);           // u
        if (blk == 2) {
            vcomb(Wp, v2, v3, buf, tid, wv, lane);
            vcomb(Wk, v3, v4, buf, tid, wv, lane);       // p1
            if (tid < DD) ws[P1_OFF + tid] = v4[tid];
        } else {
            vcomb(Wx, v2, v3, buf, tid, wv, lane);       // w1
            vcomb(Wp, v3, v4, buf, tid, wv, lane);
            vcomb(Wk, v4, v0, buf, tid, wv, lane);       // p2
            if (tid < DD) ws[P2_OFF + tid] = v0[tid];
        }
        return;
    }

    // blocks 4..7 start from Wd rows
    for (int r = tid; r < 3 * DD; r += 1024) mW[r / DD][r % DD] = Wd[r];
    __syncthreads();

    if (blk == 4) {
        rowcomb3(Wx, mW, m0, buf, tid, wv, lane);        // A2 = Wd@Wx
        rowcomb3(Wx, m0, m1, buf, tid, wv, lane);        // A3 = Wd@Wx^2
        if (tid < DD) v1[tid] = bk[tid];
        __syncthreads();
        bpass(Wp, bp, bx, v1, vB, wv, lane);             // B
        if (wv < 3) {
            float ca = 0.f, cb = 0.f, cc = 0.f;
            for (int j = lane; j < DD; j += 64) {
                const float b = vB[j];
                ca += m0[wv][j] * b; cb += m1[wv][j] * b; cc += mW[wv][j] * b;
            }
            ca = wred(ca); cb = wred(cb); cc = wred(cc);
            if (lane == 0) {
                ws[C3A + wv] = ca;
                ws[C3B + wv] = cb;
                ws[C3C + wv] = cc + bd[wv];
            }
        }
        rowcomb3(Wx, m1, m0, buf, tid, wv, lane);        // D0 = Wd@Wx^3
        for (int r = tid; r < 3 * DD; r += 1024) ws[D0_OFF + r] = m0[r / DD][r % DD];
        return;
    }
    if (blk == 5) {
        rowcomb3(Wp, mW, m0, buf, tid, wv, lane);
        rowcomb3(Wk, m0, m1, buf, tid, wv, lane);        // D3
        for (int r = tid; r < 3 * DD; r += 1024) ws[D3_OFF + r] = m1[r / DD][r % DD];
        return;
    }
    if (blk == 6) {
        rowcomb3(Wx, mW, m0, buf, tid, wv, lane);
        rowcomb3(Wp, m0, m1, buf, tid, wv, lane);
        rowcomb3(Wk, m1, m0, buf, tid, wv, lane);        // D2
        for (int r = tid; r < 3 * DD; r += 1024) ws[D2_OFF + r] = m0[r / DD][r % DD];
        return;
    }
    {   // blk 7
        rowcomb3(Wx, mW, m0, buf, tid, wv, lane);
        rowcomb3(Wx, m0, m1, buf, tid, wv, lane);
        rowcomb3(Wp, m1, m0, buf, tid, wv, lane);
        rowcomb3(Wk, m0, m1, buf, tid, wv, lane);        // D1
        for (int r = tid; r < 3 * DD; r += 1024) ws[D1_OFF + r] = m1[r / DD][r % DD];
    }
}

// ---------------------------------------------------------------------------
// build_tables: 2048 blocks x 256 (8192 waves, ~6 rows each). The 12
// projection vectors are held in VGPRs (lane-partitioned, 24 float4/lane),
// so the hot loop is: 2 global float4 loads, 96 FMA, 12 interleaved
// butterflies. No LDS at all.
// ---------------------------------------------------------------------------
__global__ __launch_bounds__(256) void build_tables(
    const float* __restrict__ emb, float* __restrict__ ws)
{
    const int tid  = threadIdx.x;
    const int lane = tid & 63;
    const int gw   = (blockIdx.x * 256 + tid) >> 6;   // global wave id
    const int nw   = (gridDim.x * 256) >> 6;

    const int voff[12] = {P1_OFF, P2_OFF,
                          D1_OFF, D1_OFF + DD, D1_OFF + 2 * DD,
                          D2_OFF, D2_OFF + DD, D2_OFF + 2 * DD,
                          D3_OFF, D3_OFF + DD, D3_OFF + 2 * DD,
                          U_OFF};
    float4 vA[12], vB[12];
    #pragma unroll
    for (int k = 0; k < 12; ++k) {
        const float4* p = (const float4*)(ws + voff[k]);
        vA[k] = p[lane];
        vB[k] = (lane < 11) ? p[64 + lane] : float4{0, 0, 0, 0};
    }

    for (int v = gw; v < VV; v += nw) {
        const float4* er = (const float4*)(emb + (size_t)v * DD);
        const float4 e0 = er[lane];
        float4 e1{0, 0, 0, 0};
        if (lane < 11) e1 = er[64 + lane];

        float acc[12];
        #pragma unroll
        for (int k = 0; k < 12; ++k) {
            acc[k] = e0.x * vA[k].x + e0.y * vA[k].y
                   + e0.z * vA[k].z + e0.w * vA[k].w
                   + e1.x * vB[k].x + e1.y * vB[k].y
                   + e1.z * vB[k].z + e1.w * vB[k].w;
        }
        #pragma unroll
        for (int off = 32; off; off >>= 1) {
            #pragma unroll
            for (int k = 0; k < 12; ++k) acc[k] += __shfl_xor(acc[k], off);
        }
        if (lane == 0) {
            float4* tp = (float4*)(ws + TAB_OFF + (size_t)v * 12);
            tp[0] = float4{acc[0], acc[1], acc[2],  acc[3]};
            tp[1] = float4{acc[4], acc[5], acc[6],  acc[7]};
            tp[2] = float4{acc[8], acc[9], acc[10], acc[11]};
        }
    }
}

// ---------------------------------------------------------------------------
// k_hops: 512 blocks x 512 threads, 1 batch row per block. No embedding
// gathers: per-token 48B tab row, all hop math is scalars + wave reductions.
// ---------------------------------------------------------------------------
__global__ __launch_bounds__(512) void k_hops(
    const int* __restrict__ text, const int* __restrict__ asp,
    const float* __restrict__ emb, float* __restrict__ out,
    const float* __restrict__ ws)
{
    const int b    = blockIdx.x;
    const int tid  = threadIdx.x;
    const int wv   = tid >> 6;     // 0..7
    const int lane = tid & 63;

    __shared__ __align__(16) float X0s[304];
    __shared__ float rlen[8];
    __shared__ float rp[8][6];
    __shared__ float qsv;

    const float ck  = ws[CK];
    const float cqs = ws[CQS];

    const int t = text[b * SS + tid];
    {
        const unsigned long long bal = __ballot(t != 0);
        if (lane == 0) rlen[wv] = (float)__popcll(bal);
    }
    const float4* tr = (const float4*)(ws + TAB_OFF + (size_t)t * 12);
    const float4 tA = tr[0];
    const float4 tB = tr[1];
    const float4 tC = tr[2];

    if (tid < DD) {
        float na = 0.f, a = 0.f;
        #pragma unroll
        for (int k = 0; k < 8; ++k) {
            const int idx = asp[b * 8 + k];
            na += (idx != 0) ? 1.0f : 0.0f;
            a += emb[(size_t)idx * DD + tid];
        }
        X0s[tid] = a / na;
    }
    __syncthreads();

    float lenf; int s0;
    {
        float l = 0.f;
        #pragma unroll
        for (int w = 0; w < 8; ++w) l += rlen[w];
        lenf = l; s0 = SS - (int)l;
    }
    const bool act = (tid >= s0);
    const float wg  = act ? (1.0f - (float)(tid - s0) / lenf) : 0.f;
    const float ksr = wg * tC.w + ck;            // eu = tC.w

    // init dots (wave 0): X0·u, X0·w1, X0·w2, D0@X0
    float aw1 = 0.f, aw2 = 0.f, d12 = 0.f, o0 = 0.f, o1 = 0.f, o2 = 0.f;
    if (wv == 0) {
        float pq = 0.f, p1 = 0.f, p2 = 0.f, pd0 = 0.f, pd1 = 0.f, pd2 = 0.f;
        for (int j = lane; j < DD; j += 64) {
            const float x = X0s[j];
            pq  += x * ws[UQWX_OFF + j];
            p1  += x * ws[W1_OFF + j];
            p2  += x * ws[W2_OFF + j];
            pd0 += x * ws[D0_OFF + j];
            pd1 += x * ws[D0_OFF + DD + j];
            pd2 += x * ws[D0_OFF + 2 * DD + j];
        }
        pq = wred(pq); aw1 = wred(p1); aw2 = wred(p2);
        o0 = wred(pd0) + ws[C3A + 0] + ws[C3B + 0] + ws[C3C + 0];
        o1 = wred(pd1) + ws[C3A + 1] + ws[C3B + 1] + ws[C3C + 1];
        o2 = wred(pd2) + ws[C3A + 2] + ws[C3B + 2] + ws[C3C + 2];
        if (lane == 0) qsv = pq + cqs;
    }
    __syncthreads();

    const float bu = ws[BU], bw1 = ws[BW1];

    #pragma unroll
    for (int h = 0; h < 3; ++h) {
        const float qs = qsv;
        float p = 0.f;
        if (act) p = fast_exp_tanh(ksr + qs);
        const float pw = p * wg;
        float u0 = p, u1, u2, u3, u4 = 0.f, u5 = 0.f;
        if (h == 0)      { u1 = pw*tA.x; u2 = pw*tA.y; u3 = pw*tA.z; u4 = pw*tA.w; u5 = pw*tB.x; }
        else if (h == 1) { u1 = pw*tA.x; u2 = pw*tB.y; u3 = pw*tB.z; u4 = pw*tB.w; }
        else             { u1 = pw*tC.x; u2 = pw*tC.y; u3 = pw*tC.z; }
        u0 = wred(u0); u1 = wred(u1); u2 = wred(u2); u3 = wred(u3);
        if (h == 0) { u4 = wred(u4); u5 = wred(u5); }
        else if (h == 1) { u4 = wred(u4); }
        if (lane == 0) {
            rp[wv][0] = u0; rp[wv][1] = u1; rp[wv][2] = u2;
            rp[wv][3] = u3; rp[wv][4] = u4; rp[wv][5] = u5;
        }
        __syncthreads();
        if (wv == 0) {
            float s0_ = 0, s1_ = 0, s2_ = 0, s3_ = 0, s4_ = 0, s5_ = 0;
            #pragma unroll
            for (int w = 0; w < 8; ++w) {
                s0_ += rp[w][0]; s1_ += rp[w][1]; s2_ += rp[w][2];
                s3_ += rp[w][3]; s4_ += rp[w][4]; s5_ += rp[w][5];
            }
            const float sp  = s0_ + (float)s0 * fast_exp_tanh(ck + qs);
            const float isp = 1.0f / sp;
            if (h == 0) {
                d12 = isp * s2_;
                o0 += isp * s3_; o1 += isp * s4_; o2 += isp * s5_;
                if (lane == 0) qsv = isp * s1_ + aw1 + bu + cqs;
            } else if (h == 1) {
                o0 += isp * s2_; o1 += isp * s3_; o2 += isp * s4_;
                if (lane == 0) qsv = isp * s1_ + d12 + aw2 + bw1 + bu + cqs;
            } else if (lane == 0) {
                out[b * 3 + 0] = o0 + isp * s1_;
                out[b * 3 + 1] = o1 + isp * s2_;
                out[b * 3 + 2] = o2 + isp * s3_;
            }
        }
        if (h < 2) __syncthreads();
    }
}

extern "C" void kernel_launch(void* const* d_in, const int* in_sizes, int n_in,
                              void* d_out, int out_size, void* d_ws, size_t ws_size,
                              hipStream_t stream)
{
    const int*   text = (const int*)d_in[0];
    const int*   asp  = (const int*)d_in[1];
    const float* emb  = (const float*)d_in[2];
    const float* Wx   = (const float*)d_in[3];
    const float* bx   = (const float*)d_in[4];
    const float* Wk   = (const float*)d_in[5];
    const float* bk   = (const float*)d_in[6];
    const float* Wq   = (const float*)d_in[7];
    const float* bq   = (const float*)d_in[8];
    const float* wm   = (const float*)d_in[9];
    const float* Wp   = (const float*)d_in[10];
    const float* bp   = (const float*)d_in[11];
    const float* Wd   = (const float*)d_in[12];
    const float* bd   = (const float*)d_in[13];
    float* out = (float*)d_out;
    float* ws  = (float*)d_ws;

    pre<<<8, 1024, 0, stream>>>(Wk, bk, Wq, bq, wm, Wp, bp, Wx, bx, Wd, bd, ws);
    build_tables<<<2048, 256, 0, stream>>>(emb, ws);
    k_hops<<<512, 512, 0, stream>>>(text, asp, emb, out, ws);
}